// Round 1
// 552.825 us; speedup vs baseline: 1.3304x; 1.3304x over previous
//
#include <hip/hip_runtime.h>
#include <stdint.h>

typedef unsigned int u32;
typedef unsigned short u16;

typedef __attribute__((ext_vector_type(8))) short bf16x8;
typedef __attribute__((ext_vector_type(8))) unsigned short u16x8;
typedef __attribute__((ext_vector_type(4))) float f32x4;

// f32 -> bf16 round-to-nearest-even
__device__ __forceinline__ u16 f2bfu(float f) {
  union { float f; u32 u; } v; v.f = f;
  return (u16)((v.u + 0x7FFFu + ((v.u >> 16) & 1u)) >> 16);
}

// async global->LDS, 16B per lane; lds ptr must be base + lane*16 (linear)
__device__ __forceinline__ void gload16(const void* g, void* l) {
  __builtin_amdgcn_global_load_lds(
      (const __attribute__((address_space(1))) void*)g,
      (__attribute__((address_space(3))) void*)l, 16, 0, 0);
}

// ---------- Threefry-2x32/20 (JAX PRNG) ----------
__device__ __forceinline__ u32 rotl32(u32 x, int r) { return (x << r) | (x >> (32 - r)); }

__device__ __forceinline__ uint2 threefry2x32(u32 k0, u32 k1, u32 x0, u32 x1) {
  u32 ks2 = k0 ^ k1 ^ 0x1BD11BDAu;
  x0 += k0; x1 += k1;
#define TF_G(a,b,c,d) { x0 += x1; x1 = rotl32(x1,a); x1 ^= x0; \
                        x0 += x1; x1 = rotl32(x1,b); x1 ^= x0; \
                        x0 += x1; x1 = rotl32(x1,c); x1 ^= x0; \
                        x0 += x1; x1 = rotl32(x1,d); x1 ^= x0; }
  TF_G(13,15,26,6);  x0 += k1;  x1 += ks2 + 1u;
  TF_G(17,29,16,24); x0 += ks2; x1 += k0  + 2u;
  TF_G(13,15,26,6);  x0 += k0;  x1 += k1  + 3u;
  TF_G(17,29,16,24); x0 += k1;  x1 += ks2 + 4u;
  TF_G(13,15,26,6);  x0 += ks2; x1 += k0  + 5u;
#undef TF_G
  return make_uint2(x0, x1);
}

// ======================================================================
// Kernel 0: one-pass bf16 pre-convert of X (k-tiled, padded, pre-swizzled)
// and W (k-tiled per (mod,ot), pre-swizzled).
//   X slot y (768 slots): [16 ks][64 l][32 k] bf16 = 64 KB, 16B-chunk seg
//     stored at seg ^ ((l>>1)&3)  (so linear global_load_lds lands swizzled)
//   W tile (mod*4+ot)*16+ks: [128 row][32 k] bf16 = 8 KB, seg ^ ((row>>1)&3)
// ======================================================================
__global__ __launch_bounds__(256) void convert_kernel(
    const float* __restrict__ rgb, const float* __restrict__ depth,
    const float* __restrict__ mmw, const float* __restrict__ lid,
    const float* __restrict__ conv_w, u16* __restrict__ Wc, u16* __restrict__ Xc)
{
  const int bid = blockIdx.x, tid = threadIdx.x;
  float4 v0 = make_float4(0.f, 0.f, 0.f, 0.f), v1 = v0;
  char* dst;
  if (bid < 12288) {                       // X part: (slot y, ks) per block
    const int y = bid >> 4, ks = bid & 15;
    const int l = tid >> 2, seg = tid & 3;
    const float* xp; size_t row = 0; bool valid = true;
    if (y < 256)      { xp = rgb;   row = (size_t)y * 49 + l;         valid = (l < 49); }
    else if (y < 512) { xp = depth; row = (size_t)(y - 256) * 49 + l; valid = (l < 49); }
    else if (y < 640) { xp = mmw;   row = (size_t)(y - 512) * 64 + l; }
    else              { xp = lid;   row = (size_t)(y - 640) * 64 + l; }
    if (valid) {
      const float* s = xp + row * 512 + ks * 32 + seg * 8;
      v0 = *(const float4*)s; v1 = *(const float4*)(s + 4);
    }
    dst = (char*)Xc + (size_t)y * 65536 + ks * 4096 + l * 64 + ((seg ^ ((l >> 1) & 3)) << 4);
  } else {                                 // W part: 2 blocks per 8KB tile
    const int t = bid - 12288;             // 0..511
    const int tile = t >> 1, half = t & 1; // tile = (mod*4+ot)*16+ks
    const int row = (tid >> 2) + half * 64, seg = tid & 3;
    const float* s = conv_w + (size_t)((tile >> 4) * 128 + row) * 512 + (tile & 15) * 32 + seg * 8;
    v0 = *(const float4*)s; v1 = *(const float4*)(s + 4);
    dst = (char*)Wc + (size_t)tile * 8192 + row * 64 + ((seg ^ ((row >> 1) & 3)) << 4);
  }
  u16x8 pk;
  pk[0] = f2bfu(v0.x); pk[1] = f2bfu(v0.y); pk[2] = f2bfu(v0.z); pk[3] = f2bfu(v0.w);
  pk[4] = f2bfu(v1.x); pk[5] = f2bfu(v1.y); pk[6] = f2bfu(v1.z); pk[7] = f2bfu(v1.w);
  *(u16x8*)dst = pk;
}

// ======================================================================
// Kernel 1 (fused): blocks 0..255 = FPS (verbatim math), blocks 256+ =
// branch conv via bf16 MFMA with global_load_lds 2-phase pipeline.
// LDS map (branch): [0,8192)+[8192,16384) Wb dbuf; [16384,20480)+[20480,24576)
// Xb dbuf; Cb reuses [0,16896) after K-loop; hsB [24576,47104) stride 88;
// lw2 [47104,51712); bnA/bnC/lbs [51712,52864). FPS uses [0,49188).
// ======================================================================
#define FSMEM_SZ 52864

__global__ __launch_bounds__(256) void fused_kernel(
    const float* __restrict__ pts, int* __restrict__ fps_idx,
    const u16* __restrict__ Wc, const u16* __restrict__ Xc,
    const float* __restrict__ conv_b,
    const float* __restrict__ bn_g, const float* __restrict__ bn_b,
    const float* __restrict__ bn_m, const float* __restrict__ bn_v,
    const float* __restrict__ lin_w_img, const float* __restrict__ lin_b_img,
    const float* __restrict__ lin_w_pc, const float* __restrict__ lin_b_pc,
    float* __restrict__ out)
{
  __shared__ __align__(16) char sm[FSMEM_SZ];
  const int tid = threadIdx.x;

  if (blockIdx.x < 256) {
    // ---------------- FPS (bit-exact, unchanged math) ----------------
    float* xs = (float*)sm;
    float* ys = (float*)(sm + 16384);
    float* zs = (float*)(sm + 32768);
    float* rv = (float*)(sm + 49152);
    int*   ri = (int*)(sm + 49168);
    int*   fsh = (int*)(sm + 49184);
    const int b = blockIdx.x;
    const float* pb = pts + (size_t)b * 4096 * 3;

    for (int i = tid; i < 12288; i += 256) {
      float v = pb[i];
      int n = i / 3, c = i - n * 3;
      float* dstp = (c == 0) ? xs : (c == 1) ? ys : zs;
      dstp[n] = v;
    }
    float dreg[16];
#pragma unroll
    for (int i = 0; i < 16; i++) dreg[i] = 1e10f;
    __syncthreads();

    uint2 k2 = threefry2x32(0u, 42u, 0u, 1u);
    uint2 r  = threefry2x32(k2.x, k2.y, 0u, (u32)b);
    int far  = (int)((r.x ^ r.y) & 4095u);

    for (int s = 0; s < 128; s++) {
      if (tid == 0) fps_idx[b * 128 + s] = far;
      float cx = xs[far], cy = ys[far], cz = zs[far];
      float bestv = -1.f; int besti = 0x7FFFFFFF;
#pragma unroll
      for (int i = 0; i < 16; i++) {
        int n = tid + (i << 8);
        float dx = __fsub_rn(xs[n], cx);
        float dy = __fsub_rn(ys[n], cy);
        float dz = __fsub_rn(zs[n], cz);
        float d  = __fadd_rn(__fadd_rn(__fmul_rn(dx, dx), __fmul_rn(dy, dy)), __fmul_rn(dz, dz));
        float nd = fminf(dreg[i], d);
        dreg[i] = nd;
        if (nd > bestv) { bestv = nd; besti = n; }
      }
#pragma unroll
      for (int off = 1; off < 64; off <<= 1) {
        float ov = __shfl_xor(bestv, off, 64);
        int   oi = __shfl_xor(besti, off, 64);
        if (ov > bestv || (ov == bestv && oi < besti)) { bestv = ov; besti = oi; }
      }
      if ((tid & 63) == 0) { rv[tid >> 6] = bestv; ri[tid >> 6] = besti; }
      __syncthreads();
      if (tid == 0) {
        float bv = rv[0]; int bi = ri[0];
#pragma unroll
        for (int w = 1; w < 4; w++)
          if (rv[w] > bv || (rv[w] == bv && ri[w] < bi)) { bv = rv[w]; bi = ri[w]; }
        *fsh = bi;
      }
      __syncthreads();
      far = *fsh;
    }
    return;
  }

  // ---------------- branch GEMM path ----------------
  const int g  = (int)blockIdx.x - 256;
  const int ot = g & 3;
  const int y  = g >> 2;
  int mod, bidx = 0, bg = 0;
  if      (y < 256) { mod = 0; bidx = y; }
  else if (y < 512) { mod = 1; bidx = y - 256; }
  else if (y < 640) { mod = 2; bg   = y - 512; }
  else              { mod = 3; bg   = y - 640; }
  const bool img = (mod < 2);
  const int  L   = img ? 49 : 32;
  const float* lw = img ? (lin_w_img + mod * 32 * 49) : (lin_w_pc + (mod - 2) * 32 * 32);
  const float* lb = img ? (lin_b_img + mod * 32)      : (lin_b_pc + (mod - 2) * 32);

  u16*   lw2 = (u16*)(sm + 47104);
  float* bnA = (float*)(sm + 51712);
  float* bnC = (float*)(sm + 52224);
  float* lbs = (float*)(sm + 52736);
  u16*   hsB = (u16*)(sm + 24576);
  float* Cb  = (float*)sm;

  for (int i = tid; i < 32 * 64; i += 256) {
    int kk = i >> 6, l = i & 63;
    float v = (l < L) ? lw[kk * L + l] : 0.f;
    lw2[kk * 72 + l] = f2bfu(v);
  }
  if (tid < 32) lbs[tid] = lb[tid];
  if (tid < 128) {
    int o = mod * 512 + ot * 128 + tid;
    float sc = bn_g[o] / sqrtf(bn_v[o] + 1e-5f);
    bnA[tid] = sc;
    bnC[tid] = (conv_b[o] - bn_m[o]) * sc + bn_b[o];
  }

  const int lane = tid & 63, w = tid >> 6, quad = lane >> 4, lm = lane & 15;
  const int xorq = ((lm >> 1) & 3) << 4;     // read-side swizzle (matches convert)
  const int soff = w * 1024 + lane * 16;     // linear per-lane stage offset

  const char* wcB = (const char*)Wc + (size_t)(mod * 4 + ot) * (16 * 8192);
  const char* xcB = (const char*)Xc + (size_t)y * 65536;

  f32x4 acc[2][4];
#pragma unroll
  for (int mi = 0; mi < 2; mi++)
#pragma unroll
    for (int nt = 0; nt < 4; nt++) acc[mi][nt] = (f32x4){0.f, 0.f, 0.f, 0.f};

  // drain prologue loads so manual vmcnt counting is exact
  asm volatile("s_waitcnt vmcnt(0)" ::: "memory");
  // prologue: stage ks=0 into buffer 0 (3 gloads: 8KB W + 4KB X)
  gload16(wcB + soff,        sm + soff);
  gload16(wcB + soff + 4096, sm + soff + 4096);
  gload16(xcB + soff,        sm + 16384 + soff);

#pragma unroll
  for (int ks = 0; ks < 16; ks++) {
    const int cur = ks & 1;
    if (ks < 15) {                         // issue next-tile loads first
      const char* wsrc = wcB + (ks + 1) * 8192;
      const char* xsrc = xcB + (ks + 1) * 4096;
      char* wd = sm + (cur ^ 1) * 8192;
      char* xd = sm + 16384 + (cur ^ 1) * 4096;
      gload16(wsrc + soff,        wd + soff);
      gload16(wsrc + soff + 4096, wd + soff + 4096);
      gload16(xsrc + soff,        xd + soff);
      asm volatile("s_waitcnt vmcnt(3)" ::: "memory");  // cur tile landed
    } else {
      asm volatile("s_waitcnt vmcnt(0)" ::: "memory");
    }
    __builtin_amdgcn_s_barrier();          // all waves' cur-tile loads landed
    asm volatile("" ::: "memory");
    const char* wbc = sm + cur * 8192;
    const char* xbc = sm + 16384 + cur * 4096;
    bf16x8 af[2], bfr[4];
#pragma unroll
    for (int mi = 0; mi < 2; mi++)
      af[mi] = *(const bf16x8*)(wbc + w * 2048 + mi * 1024 + lm * 64 + ((quad * 16) ^ xorq));
#pragma unroll
    for (int nt = 0; nt < 4; nt++)
      bfr[nt] = *(const bf16x8*)(xbc + nt * 1024 + lm * 64 + ((quad * 16) ^ xorq));
#pragma unroll
    for (int mi = 0; mi < 2; mi++)
#pragma unroll
      for (int nt = 0; nt < 4; nt++)
        acc[mi][nt] = __builtin_amdgcn_mfma_f32_16x16x32_bf16(af[mi], bfr[nt], acc[mi][nt], 0, 0, 0);
    asm volatile("s_waitcnt lgkmcnt(0)" ::: "memory");   // reads done pre-barrier
    __builtin_amdgcn_s_barrier();          // safe to overwrite cur^1 next iter
  }

  // ---- BN + ReLU -> hsB (bf16); C/D layout: col=lane&15, row=quad*4+reg ----
#pragma unroll
  for (int mi = 0; mi < 2; mi++)
#pragma unroll
    for (int nt = 0; nt < 4; nt++)
#pragma unroll
      for (int r = 0; r < 4; r++) {
        int o_loc = w * 32 + mi * 16 + quad * 4 + r;
        int l     = nt * 16 + lm;
        float v = acc[mi][nt][r] * bnA[o_loc] + bnC[o_loc];
        hsB[o_loc * 88 + l] = f2bfu(v > 0.f ? v : 0.f);
      }
  __syncthreads();

  // ---- stage B: out[b][mod*32+kk][o] = relu(hs @ lw^T + lb), via MFMA ----
  const int npass = img ? 1 : 2;
  const int nkt   = img ? 2 : 1;
  for (int p = 0; p < npass; p++) {
    f32x4 c2[2][2];
#pragma unroll
    for (int mi = 0; mi < 2; mi++)
#pragma unroll
      for (int nt2 = 0; nt2 < 2; nt2++) c2[mi][nt2] = (f32x4){0.f, 0.f, 0.f, 0.f};
    for (int kt = 0; kt < nkt; kt++) {
      int aoff = img ? kt * 32 : p * 32;
      int boff = img ? kt * 32 : 0;
      bf16x8 a2[2], b2[2];
#pragma unroll
      for (int mi = 0; mi < 2; mi++)
        a2[mi] = *(const bf16x8*)&hsB[(w * 32 + mi * 16 + lm) * 88 + aoff + quad * 8];
#pragma unroll
      for (int nt2 = 0; nt2 < 2; nt2++)
        b2[nt2] = *(const bf16x8*)&lw2[(nt2 * 16 + lm) * 72 + boff + quad * 8];
#pragma unroll
      for (int mi = 0; mi < 2; mi++)
#pragma unroll
        for (int nt2 = 0; nt2 < 2; nt2++)
          c2[mi][nt2] = __builtin_amdgcn_mfma_f32_16x16x32_bf16(a2[mi], b2[nt2], c2[mi][nt2], 0, 0, 0);
    }
#pragma unroll
    for (int mi = 0; mi < 2; mi++)
#pragma unroll
      for (int nt2 = 0; nt2 < 2; nt2++)
#pragma unroll
        for (int r = 0; r < 4; r++) {
          int kk    = nt2 * 16 + lm;
          int o_loc = w * 32 + mi * 16 + quad * 4 + r;
          float v = c2[mi][nt2][r] + lbs[kk];
          Cb[kk * 132 + o_loc] = v > 0.f ? v : 0.f;
        }
    __syncthreads();
    int b_out = img ? bidx : (bg * 2 + p);
    for (int i = tid; i < 4096; i += 256) {
      int kk = i >> 7, j = i & 127;
      out[((size_t)b_out * 128 + mod * 32 + kk) * 512 + ot * 128 + j] = Cb[kk * 132 + j];
    }
    if (p + 1 < npass) __syncthreads();
  }
}

// ======================================================================
// Fallback path (used only if workspace is too small): previous verified
// kernels, byte-for-byte behavior.
// ======================================================================
#define WB_OFF   0
#define XB_OFF   8192
#define CB_OFF   0
#define HS_OFF   16896
#define LW2_OFF  39424
#define BNA_OFF  44032
#define BNC_OFF  44544
#define LBS_OFF  45056
#define SMEM_SZ  45184

__global__ __launch_bounds__(256) void branch_kernel(
    const float* __restrict__ x0p, const float* __restrict__ x1p,
    const float* __restrict__ x2p, const float* __restrict__ x3p,
    const float* __restrict__ conv_w, const float* __restrict__ conv_b,
    const float* __restrict__ bn_g, const float* __restrict__ bn_b,
    const float* __restrict__ bn_m, const float* __restrict__ bn_v,
    const float* __restrict__ lin_w_img, const float* __restrict__ lin_b_img,
    const float* __restrict__ lin_w_pc, const float* __restrict__ lin_b_pc,
    float* __restrict__ out)
{
  __shared__ __align__(16) char sm[SMEM_SZ];
  u16*   Wb  = (u16*)(sm + WB_OFF);
  u16*   Xb  = (u16*)(sm + XB_OFF);
  float* Cb  = (float*)(sm + CB_OFF);
  u16*   hsB = (u16*)(sm + HS_OFF);
  u16*   lw2 = (u16*)(sm + LW2_OFF);
  float* bnA = (float*)(sm + BNA_OFF);
  float* bnC = (float*)(sm + BNC_OFF);
  float* lbs = (float*)(sm + LBS_OFF);

  const int ot  = blockIdx.x;
  const int tid = threadIdx.x;
  int y = blockIdx.y;
  int mod, bidx = 0, bg = 0;
  if      (y < 256) { mod = 0; bidx = y; }
  else if (y < 512) { mod = 1; bidx = y - 256; }
  else if (y < 640) { mod = 2; bg   = y - 512; }
  else              { mod = 3; bg   = y - 640; }
  const bool img = (mod < 2);
  const int  L   = img ? 49 : 32;
  const float* xp = (mod == 0) ? x0p : (mod == 1) ? x1p : (mod == 2) ? x2p : x3p;
  const float* lw = img ? (lin_w_img + mod * 32 * 49) : (lin_w_pc + (mod - 2) * 32 * 32);
  const float* lb = img ? (lin_b_img + mod * 32)      : (lin_b_pc + (mod - 2) * 32);

  for (int i = tid; i < 32 * 64; i += 256) {
    int kk = i >> 6, l = i & 63;
    float v = (l < L) ? lw[kk * L + l] : 0.f;
    lw2[kk * 72 + l] = f2bfu(v);
  }
  if (tid < 32) lbs[tid] = lb[tid];
  if (tid < 128) {
    int o = mod * 512 + ot * 128 + tid;
    float sc = bn_g[o] / sqrtf(bn_v[o] + 1e-5f);
    bnA[tid] = sc;
    bnC[tid] = (conv_b[o] - bn_m[o]) * sc + bn_b[o];
  }

  const int lane = tid & 63, w = tid >> 6, quad = lane >> 4, lm = lane & 15;
  const float* wbase = conv_w + (size_t)(mod * 512 + ot * 128) * 512;

  f32x4 acc[2][4];
#pragma unroll
  for (int mi = 0; mi < 2; mi++)
#pragma unroll
    for (int nt = 0; nt < 4; nt++) acc[mi][nt] = (f32x4){0.f, 0.f, 0.f, 0.f};

  for (int ks = 0; ks < 16; ks++) {
    int k0 = ks * 32;
    __syncthreads();
    for (int i = tid; i < 1024; i += 256) {
      int row = i >> 3, seg = i & 7;
      float4 v = *(const float4*)(wbase + (size_t)row * 512 + k0 + seg * 4);
      u16* d = &Wb[row * 32 + seg * 4];
      d[0] = f2bfu(v.x); d[1] = f2bfu(v.y); d[2] = f2bfu(v.z); d[3] = f2bfu(v.w);
    }
    for (int i = tid; i < 512; i += 256) {
      int l = i >> 3, seg = i & 7;
      float4 v = make_float4(0.f, 0.f, 0.f, 0.f);
      if (img) {
        if (l < 49) v = *(const float4*)(xp + (size_t)(bidx * 49 + l) * 512 + k0 + seg * 4);
      } else {
        v = *(const float4*)(xp + (size_t)(bg * 64 + l) * 512 + k0 + seg * 4);
      }
      u16* d = &Xb[l * 32 + seg * 4];
      d[0] = f2bfu(v.x); d[1] = f2bfu(v.y); d[2] = f2bfu(v.z); d[3] = f2bfu(v.w);
    }
    __syncthreads();
    bf16x8 af[2], bfr[4];
#pragma unroll
    for (int mi = 0; mi < 2; mi++)
      af[mi] = *(const bf16x8*)&Wb[(w * 32 + mi * 16 + lm) * 32 + quad * 8];
#pragma unroll
    for (int nt = 0; nt < 4; nt++)
      bfr[nt] = *(const bf16x8*)&Xb[(nt * 16 + lm) * 32 + quad * 8];
#pragma unroll
    for (int mi = 0; mi < 2; mi++)
#pragma unroll
      for (int nt = 0; nt < 4; nt++)
        acc[mi][nt] = __builtin_amdgcn_mfma_f32_16x16x32_bf16(af[mi], bfr[nt], acc[mi][nt], 0, 0, 0);
  }
  __syncthreads();

#pragma unroll
  for (int mi = 0; mi < 2; mi++)
#pragma unroll
    for (int nt = 0; nt < 4; nt++)
#pragma unroll
      for (int r = 0; r < 4; r++) {
        int o_loc = w * 32 + mi * 16 + quad * 4 + r;
        int l     = nt * 16 + lm;
        float v = acc[mi][nt][r] * bnA[o_loc] + bnC[o_loc];
        hsB[o_loc * 88 + l] = f2bfu(v > 0.f ? v : 0.f);
      }
  __syncthreads();

  const int npass = img ? 1 : 2;
  const int nkt   = img ? 2 : 1;
  for (int p = 0; p < npass; p++) {
    f32x4 c2[2][2];
#pragma unroll
    for (int mi = 0; mi < 2; mi++)
#pragma unroll
      for (int nt2 = 0; nt2 < 2; nt2++) c2[mi][nt2] = (f32x4){0.f, 0.f, 0.f, 0.f};
    for (int kt = 0; kt < nkt; kt++) {
      int aoff = img ? kt * 32 : p * 32;
      int boff = img ? kt * 32 : 0;
      bf16x8 a2[2], b2[2];
#pragma unroll
      for (int mi = 0; mi < 2; mi++)
        a2[mi] = *(const bf16x8*)&hsB[(w * 32 + mi * 16 + lm) * 88 + aoff + quad * 8];
#pragma unroll
      for (int nt2 = 0; nt2 < 2; nt2++)
        b2[nt2] = *(const bf16x8*)&lw2[(nt2 * 16 + lm) * 72 + boff + quad * 8];
#pragma unroll
      for (int mi = 0; mi < 2; mi++)
#pragma unroll
        for (int nt2 = 0; nt2 < 2; nt2++)
          c2[mi][nt2] = __builtin_amdgcn_mfma_f32_16x16x32_bf16(a2[mi], b2[nt2], c2[mi][nt2], 0, 0, 0);
    }
#pragma unroll
    for (int mi = 0; mi < 2; mi++)
#pragma unroll
      for (int nt2 = 0; nt2 < 2; nt2++)
#pragma unroll
        for (int r = 0; r < 4; r++) {
          int kk    = nt2 * 16 + lm;
          int o_loc = w * 32 + mi * 16 + quad * 4 + r;
          float v = c2[mi][nt2][r] + lbs[kk];
          Cb[kk * 132 + o_loc] = v > 0.f ? v : 0.f;
        }
    __syncthreads();
    int b_out = img ? bidx : (bg * 2 + p);
    for (int i = tid; i < 4096; i += 256) {
      int kk = i >> 7, j = i & 127;
      out[((size_t)b_out * 128 + mod * 32 + kk) * 512 + ot * 128 + j] = Cb[kk * 132 + j];
    }
    if (p + 1 < npass) __syncthreads();
  }
}

__global__ __launch_bounds__(256) void fps_kernel(const float* __restrict__ pts,
                                                  int* __restrict__ idx_out)
{
  __shared__ float xs[4096], ys[4096], zs[4096];
  __shared__ float rv[4];
  __shared__ int   ri[4];
  __shared__ int   far_sh;
  const int b = blockIdx.x, tid = threadIdx.x;
  const float* pb = pts + (size_t)b * 4096 * 3;

  for (int i = tid; i < 12288; i += 256) {
    float v = pb[i];
    int n = i / 3, c = i - n * 3;
    float* dst = (c == 0) ? xs : (c == 1) ? ys : zs;
    dst[n] = v;
  }
  float dreg[16];
#pragma unroll
  for (int i = 0; i < 16; i++) dreg[i] = 1e10f;
  __syncthreads();

  uint2 k2 = threefry2x32(0u, 42u, 0u, 1u);
  uint2 r  = threefry2x32(k2.x, k2.y, 0u, (u32)b);
  int far  = (int)((r.x ^ r.y) & 4095u);

  for (int s = 0; s < 128; s++) {
    if (tid == 0) idx_out[b * 128 + s] = far;
    float cx = xs[far], cy = ys[far], cz = zs[far];
    float bestv = -1.f; int besti = 0x7FFFFFFF;
#pragma unroll
    for (int i = 0; i < 16; i++) {
      int n = tid + (i << 8);
      float dx = __fsub_rn(xs[n], cx);
      float dy = __fsub_rn(ys[n], cy);
      float dz = __fsub_rn(zs[n], cz);
      float d  = __fadd_rn(__fadd_rn(__fmul_rn(dx, dx), __fmul_rn(dy, dy)), __fmul_rn(dz, dz));
      float nd = fminf(dreg[i], d);
      dreg[i] = nd;
      if (nd > bestv) { bestv = nd; besti = n; }
    }
#pragma unroll
    for (int off = 1; off < 64; off <<= 1) {
      float ov = __shfl_xor(bestv, off, 64);
      int   oi = __shfl_xor(besti, off, 64);
      if (ov > bestv || (ov == bestv && oi < besti)) { bestv = ov; besti = oi; }
    }
    if ((tid & 63) == 0) { rv[tid >> 6] = bestv; ri[tid >> 6] = besti; }
    __syncthreads();
    if (tid == 0) {
      float bv = rv[0]; int bi = ri[0];
#pragma unroll
      for (int w = 1; w < 4; w++)
        if (rv[w] > bv || (rv[w] == bv && ri[w] < bi)) { bv = rv[w]; bi = ri[w]; }
      far_sh = bi;
    }
    __syncthreads();
    far = far_sh;
  }
}

// ======================================================================
// Kernel 3: pos-enc MLP (unchanged)
// ======================================================================
__global__ __launch_bounds__(256) void pe_kernel(
    const float* __restrict__ pts, const int* __restrict__ fps_idx,
    const float* __restrict__ w1, const float* __restrict__ b1,
    const float* __restrict__ g1, const float* __restrict__ bb1,
    const float* __restrict__ m1, const float* __restrict__ v1,
    const float* __restrict__ w2, const float* __restrict__ b2,
    const float* __restrict__ g2, const float* __restrict__ bb2,
    const float* __restrict__ m2, const float* __restrict__ v2,
    float* __restrict__ out)
{
  __shared__ float h1T[64][132];
  __shared__ float w2s[32][132];
  const int ot = blockIdx.x;
  const int st = blockIdx.y;
  const int b  = blockIdx.z;
  const int tid = threadIdx.x;

  for (int i = tid; i < 32 * 32; i += 256) {
    int o = i >> 5, j = i & 31;
    float4 v = *(const float4*)(w2 + (size_t)(ot * 32 + o) * 128 + j * 4);
    *(float4*)&w2s[o][j * 4] = v;
  }
  {
    int s_l = tid & 63;
    int cq  = tid >> 6;
    int s   = st * 64 + s_l;
    int n   = fps_idx[b * 128 + s];
    float px = pts[((size_t)b * 4096 + n) * 3 + 0];
    float py = pts[((size_t)b * 4096 + n) * 3 + 1];
    float pz = pts[((size_t)b * 4096 + n) * 3 + 2];
    for (int cc = 0; cc < 32; cc++) {
      int c = cq * 32 + cc;
      float sc = g1[c] / sqrtf(v1[c] + 1e-5f);
      float C  = (b1[c] - m1[c]) * sc + bb1[c];
      float d  = fmaf(pz, w1[c * 3 + 2], fmaf(py, w1[c * 3 + 1], px * w1[c * 3]));
      float h  = d * sc + C;
      h1T[s_l][c] = h > 0.f ? h : 0.f;
    }
  }
  __syncthreads();

  const int tx = tid & 15, ty = tid >> 4;
  float acc[2][4];
#pragma unroll
  for (int j = 0; j < 2; j++)
#pragma unroll
    for (int i = 0; i < 4; i++) acc[j][i] = 0.f;

  for (int c = 0; c < 128; c += 4) {
    float4 wv[2];
#pragma unroll
    for (int j = 0; j < 2; j++) wv[j] = *(const float4*)&w2s[tx + 16 * j][c];
#pragma unroll
    for (int si = 0; si < 4; si++) {
      float4 hv = *(const float4*)&h1T[ty + 16 * si][c];
#pragma unroll
      for (int j = 0; j < 2; j++) {
        acc[j][si] = fmaf(hv.x, wv[j].x, acc[j][si]);
        acc[j][si] = fmaf(hv.y, wv[j].y, acc[j][si]);
        acc[j][si] = fmaf(hv.z, wv[j].z, acc[j][si]);
        acc[j][si] = fmaf(hv.w, wv[j].w, acc[j][si]);
      }
    }
  }

#pragma unroll
  for (int j = 0; j < 2; j++) {
    int o = ot * 32 + tx + 16 * j;
    float sc = g2[o] / sqrtf(v2[o] + 1e-5f);
    float C  = (b2[o] - m2[o]) * sc + bb2[o];
#pragma unroll
    for (int si = 0; si < 4; si++) {
      int s = st * 64 + ty + 16 * si;
      float v = acc[j][si] * sc + C;
      v = v > 0.f ? v : 0.f;
      size_t oi = ((size_t)b * 128 + s) * 512 + o;
      out[oi] = out[oi] + v;
    }
  }
}

// ======================================================================
extern "C" void kernel_launch(void* const* d_in, const int* in_sizes, int n_in,
                              void* d_out, int out_size, void* d_ws, size_t ws_size,
                              hipStream_t stream) {
  const float* rgb    = (const float*)d_in[0];
  const float* depth  = (const float*)d_in[1];
  const float* mmwave = (const float*)d_in[2];
  const float* lidar  = (const float*)d_in[3];
  const float* pts    = (const float*)d_in[4];
  const float* conv_w = (const float*)d_in[5];
  const float* conv_b = (const float*)d_in[6];
  const float* bn_g   = (const float*)d_in[7];
  const float* bn_b   = (const float*)d_in[8];
  const float* bn_m   = (const float*)d_in[9];
  const float* bn_v   = (const float*)d_in[10];
  const float* lwi    = (const float*)d_in[11];
  const float* lbi    = (const float*)d_in[12];
  const float* lwp    = (const float*)d_in[13];
  const float* lbp    = (const float*)d_in[14];
  const float* pw1    = (const float*)d_in[15];
  const float* pb1    = (const float*)d_in[16];
  const float* pg1    = (const float*)d_in[17];
  const float* pbb1   = (const float*)d_in[18];
  const float* pm1    = (const float*)d_in[19];
  const float* pv1    = (const float*)d_in[20];
  const float* pw2    = (const float*)d_in[21];
  const float* pb2    = (const float*)d_in[22];
  const float* pg2    = (const float*)d_in[23];
  const float* pbb2   = (const float*)d_in[24];
  const float* pm2    = (const float*)d_in[25];
  const float* pv2    = (const float*)d_in[26];
  float* out = (float*)d_out;
  int* fps_idx = (int*)d_ws;                       // [0, 131072)

  // ws layout: fps_idx 128KB | Wc 2MB bf16 | Xc 48MB bf16
  const size_t NEED = 131072 + 2097152 + (size_t)768 * 65536;  // 52,559,872
  if (ws_size >= NEED) {
    u16* Wc = (u16*)((char*)d_ws + 131072);
    u16* Xc = (u16*)((char*)d_ws + 2228224);
    convert_kernel<<<dim3(12800), 256, 0, stream>>>(rgb, depth, mmwave, lidar,
        conv_w, Wc, Xc);
    fused_kernel<<<dim3(3328), 256, 0, stream>>>(pts, fps_idx, Wc, Xc,
        conv_b, bn_g, bn_b, bn_m, bn_v, lwi, lbi, lwp, lbp, out);
  } else {
    branch_kernel<<<dim3(4, 768), 256, 0, stream>>>(rgb, depth, mmwave, lidar,
        conv_w, conv_b, bn_g, bn_b, bn_m, bn_v, lwi, lbi, lwp, lbp, out);
    fps_kernel<<<dim3(256), 256, 0, stream>>>(pts, fps_idx);
  }
  pe_kernel<<<dim3(16, 2, 256), 256, 0, stream>>>(pts, fps_idx, pw1, pb1, pg1, pbb1, pm1, pv1,
      pw2, pb2, pg2, pbb2, pm2, pv2, out);
}

// Round 2
// 444.715 us; speedup vs baseline: 1.6538x; 1.2431x over previous
//
#include <hip/hip_runtime.h>
#include <stdint.h>

typedef unsigned int u32;
typedef unsigned short u16;

typedef __attribute__((ext_vector_type(8))) short bf16x8;
typedef __attribute__((ext_vector_type(8))) unsigned short u16x8;
typedef __attribute__((ext_vector_type(4))) float f32x4;

// f32 -> bf16 round-to-nearest-even
__device__ __forceinline__ u16 f2bfu(float f) {
  union { float f; u32 u; } v; v.f = f;
  return (u16)((v.u + 0x7FFFu + ((v.u >> 16) & 1u)) >> 16);
}

// async global->LDS, 16B per lane; lds ptr must be base + lane*16 (linear)
__device__ __forceinline__ void gload16(const void* g, void* l) {
  __builtin_amdgcn_global_load_lds(
      (const __attribute__((address_space(1))) void*)g,
      (__attribute__((address_space(3))) void*)l, 16, 0, 0);
}

// ---------- Threefry-2x32/20 (JAX PRNG) ----------
__device__ __forceinline__ u32 rotl32(u32 x, int r) { return (x << r) | (x >> (32 - r)); }

__device__ __forceinline__ uint2 threefry2x32(u32 k0, u32 k1, u32 x0, u32 x1) {
  u32 ks2 = k0 ^ k1 ^ 0x1BD11BDAu;
  x0 += k0; x1 += k1;
#define TF_G(a,b,c,d) { x0 += x1; x1 = rotl32(x1,a); x1 ^= x0; \
                        x0 += x1; x1 = rotl32(x1,b); x1 ^= x0; \
                        x0 += x1; x1 = rotl32(x1,c); x1 ^= x0; \
                        x0 += x1; x1 = rotl32(x1,d); x1 ^= x0; }
  TF_G(13,15,26,6);  x0 += k1;  x1 += ks2 + 1u;
  TF_G(17,29,16,24); x0 += ks2; x1 += k0  + 2u;
  TF_G(13,15,26,6);  x0 += k0;  x1 += k1  + 3u;
  TF_G(17,29,16,24); x0 += k1;  x1 += ks2 + 4u;
  TF_G(13,15,26,6);  x0 += ks2; x1 += k0  + 5u;
#undef TF_G
  return make_uint2(x0, x1);
}

// ======================================================================
// Kernel 0: one-pass bf16 pre-convert of X (k-tiled, padded, pre-swizzled)
// and W (k-tiled per (mod,ot), pre-swizzled).
// ======================================================================
__global__ __launch_bounds__(256) void convert_kernel(
    const float* __restrict__ rgb, const float* __restrict__ depth,
    const float* __restrict__ mmw, const float* __restrict__ lid,
    const float* __restrict__ conv_w, u16* __restrict__ Wc, u16* __restrict__ Xc)
{
  const int bid = blockIdx.x, tid = threadIdx.x;
  float4 v0 = make_float4(0.f, 0.f, 0.f, 0.f), v1 = v0;
  char* dst;
  if (bid < 12288) {                       // X part: (slot y, ks) per block
    const int y = bid >> 4, ks = bid & 15;
    const int l = tid >> 2, seg = tid & 3;
    const float* xp; size_t row = 0; bool valid = true;
    if (y < 256)      { xp = rgb;   row = (size_t)y * 49 + l;         valid = (l < 49); }
    else if (y < 512) { xp = depth; row = (size_t)(y - 256) * 49 + l; valid = (l < 49); }
    else if (y < 640) { xp = mmw;   row = (size_t)(y - 512) * 64 + l; }
    else              { xp = lid;   row = (size_t)(y - 640) * 64 + l; }
    if (valid) {
      const float* s = xp + row * 512 + ks * 32 + seg * 8;
      v0 = *(const float4*)s; v1 = *(const float4*)(s + 4);
    }
    dst = (char*)Xc + (size_t)y * 65536 + ks * 4096 + l * 64 + ((seg ^ ((l >> 1) & 3)) << 4);
  } else {                                 // W part: 2 blocks per 8KB tile
    const int t = bid - 12288;             // 0..511
    const int tile = t >> 1, half = t & 1; // tile = (mod*4+ot)*16+ks
    const int row = (tid >> 2) + half * 64, seg = tid & 3;
    const float* s = conv_w + (size_t)((tile >> 4) * 128 + row) * 512 + (tile & 15) * 32 + seg * 8;
    v0 = *(const float4*)s; v1 = *(const float4*)(s + 4);
    dst = (char*)Wc + (size_t)tile * 8192 + row * 64 + ((seg ^ ((row >> 1) & 3)) << 4);
  }
  u16x8 pk;
  pk[0] = f2bfu(v0.x); pk[1] = f2bfu(v0.y); pk[2] = f2bfu(v0.z); pk[3] = f2bfu(v0.w);
  pk[4] = f2bfu(v1.x); pk[5] = f2bfu(v1.y); pk[6] = f2bfu(v1.z); pk[7] = f2bfu(v1.w);
  *(u16x8*)dst = pk;
}

// ======================================================================
// Kernel 1 (fused): blocks 0..255 = FPS (register-resident points, tree
// argmax, 1 barrier/step, setprio(1)); blocks 256+ = branch conv via bf16
// MFMA with global_load_lds 2-phase pipeline.
// ======================================================================
#define FSMEM_SZ 52864

__global__ __launch_bounds__(256) void fused_kernel(
    const float* __restrict__ pts, int* __restrict__ fps_idx,
    const u16* __restrict__ Wc, const u16* __restrict__ Xc,
    const float* __restrict__ conv_b,
    const float* __restrict__ bn_g, const float* __restrict__ bn_b,
    const float* __restrict__ bn_m, const float* __restrict__ bn_v,
    const float* __restrict__ lin_w_img, const float* __restrict__ lin_b_img,
    const float* __restrict__ lin_w_pc, const float* __restrict__ lin_b_pc,
    float* __restrict__ out)
{
  __shared__ __align__(16) char sm[FSMEM_SZ];
  const int tid = threadIdx.x;

  if (blockIdx.x < 256) {
    // ---------------- FPS (bit-exact results, faster chain) ----------------
    float* xs = (float*)sm;
    float* ys = (float*)(sm + 16384);
    float* zs = (float*)(sm + 32768);
    float* rv2 = (float*)(sm + 49152);   // [2][4]
    int*   ri2 = (int*)(sm + 49184);     // [2][4]
    const int b = blockIdx.x;
    const float* pb = pts + (size_t)b * 4096 * 3;

    __builtin_amdgcn_s_setprio(1);       // FPS chain is the block-critical path

    for (int i = tid; i < 12288; i += 256) {
      float v = pb[i];
      int n = i / 3, c = i - n * 3;
      float* dstp = (c == 0) ? xs : (c == 1) ? ys : zs;
      dstp[n] = v;
    }
    __syncthreads();

    // own 16 points in registers
    float xr[16], yr[16], zr[16], dreg[16];
#pragma unroll
    for (int i = 0; i < 16; i++) {
      int n = tid + (i << 8);
      xr[i] = xs[n]; yr[i] = ys[n]; zr[i] = zs[n];
      dreg[i] = 1e10f;
    }

    uint2 k2 = threefry2x32(0u, 42u, 0u, 1u);
    uint2 r  = threefry2x32(k2.x, k2.y, 0u, (u32)b);
    int far  = (int)((r.x ^ r.y) & 4095u);
    const int wv = tid >> 6;

    for (int s = 0; s < 128; s++) {
      if (tid == 0) fps_idx[b * 128 + s] = far;
      float cx = xs[far], cy = ys[far], cz = zs[far];
      float bv[16]; int bn[16];
#pragma unroll
      for (int i = 0; i < 16; i++) {
        float dx = __fsub_rn(xr[i], cx);
        float dy = __fsub_rn(yr[i], cy);
        float dz = __fsub_rn(zr[i], cz);
        float d  = __fadd_rn(__fadd_rn(__fmul_rn(dx, dx), __fmul_rn(dy, dy)), __fmul_rn(dz, dz));
        float nd = fminf(dreg[i], d);
        dreg[i] = nd;
        bv[i] = nd; bn[i] = tid + (i << 8);
      }
      // tree argmax over 16 local points; local indices ascend with i, so a
      // tie must keep the lower slot -> strict > is exactly the serial rule.
#define MRG(i, j) if (bv[j] > bv[i]) { bv[i] = bv[j]; bn[i] = bn[j]; }
      MRG(0, 8)  MRG(1, 9)  MRG(2, 10) MRG(3, 11)
      MRG(4, 12) MRG(5, 13) MRG(6, 14) MRG(7, 15)
      MRG(0, 4)  MRG(1, 5)  MRG(2, 6)  MRG(3, 7)
      MRG(0, 2)  MRG(1, 3)
      MRG(0, 1)
#undef MRG
      float bestv = bv[0]; int besti = bn[0];
#pragma unroll
      for (int off = 1; off < 64; off <<= 1) {
        float ov = __shfl_xor(bestv, off, 64);
        int   oi = __shfl_xor(besti, off, 64);
        if (ov > bestv || (ov == bestv && oi < besti)) { bestv = ov; besti = oi; }
      }
      const int par = s & 1;
      if ((tid & 63) == 0) { rv2[par * 4 + wv] = bestv; ri2[par * 4 + wv] = besti; }
      __syncthreads();
      // all threads merge the 4 wave results redundantly (uniform result)
      float bvv = rv2[par * 4]; int bii = ri2[par * 4];
#pragma unroll
      for (int w2 = 1; w2 < 4; w2++) {
        float wvv = rv2[par * 4 + w2]; int wii = ri2[par * 4 + w2];
        if (wvv > bvv || (wvv == bvv && wii < bii)) { bvv = wvv; bii = wii; }
      }
      far = bii;
    }
    return;
  }

  // ---------------- branch GEMM path ----------------
  const int g  = (int)blockIdx.x - 256;
  const int ot = g & 3;
  const int y  = g >> 2;
  int mod, bidx = 0, bg = 0;
  if      (y < 256) { mod = 0; bidx = y; }
  else if (y < 512) { mod = 1; bidx = y - 256; }
  else if (y < 640) { mod = 2; bg   = y - 512; }
  else              { mod = 3; bg   = y - 640; }
  const bool img = (mod < 2);
  const int  L   = img ? 49 : 32;
  const float* lw = img ? (lin_w_img + mod * 32 * 49) : (lin_w_pc + (mod - 2) * 32 * 32);
  const float* lb = img ? (lin_b_img + mod * 32)      : (lin_b_pc + (mod - 2) * 32);

  u16*   lw2 = (u16*)(sm + 47104);
  float* bnA = (float*)(sm + 51712);
  float* bnC = (float*)(sm + 52224);
  float* lbs = (float*)(sm + 52736);
  u16*   hsB = (u16*)(sm + 24576);
  float* Cb  = (float*)sm;

  for (int i = tid; i < 32 * 64; i += 256) {
    int kk = i >> 6, l = i & 63;
    float v = (l < L) ? lw[kk * L + l] : 0.f;
    lw2[kk * 72 + l] = f2bfu(v);
  }
  if (tid < 32) lbs[tid] = lb[tid];
  if (tid < 128) {
    int o = mod * 512 + ot * 128 + tid;
    float sc = bn_g[o] / sqrtf(bn_v[o] + 1e-5f);
    bnA[tid] = sc;
    bnC[tid] = (conv_b[o] - bn_m[o]) * sc + bn_b[o];
  }

  const int lane = tid & 63, w = tid >> 6, quad = lane >> 4, lm = lane & 15;
  const int xorq = ((lm >> 1) & 3) << 4;     // read-side swizzle (matches convert)
  const int soff = w * 1024 + lane * 16;     // linear per-lane stage offset

  const char* wcB = (const char*)Wc + (size_t)(mod * 4 + ot) * (16 * 8192);
  const char* xcB = (const char*)Xc + (size_t)y * 65536;

  f32x4 acc[2][4];
#pragma unroll
  for (int mi = 0; mi < 2; mi++)
#pragma unroll
    for (int nt = 0; nt < 4; nt++) acc[mi][nt] = (f32x4){0.f, 0.f, 0.f, 0.f};

  // drain prologue loads so manual vmcnt counting is exact
  asm volatile("s_waitcnt vmcnt(0)" ::: "memory");
  // prologue: stage ks=0 into buffer 0 (3 gloads: 8KB W + 4KB X)
  gload16(wcB + soff,        sm + soff);
  gload16(wcB + soff + 4096, sm + soff + 4096);
  gload16(xcB + soff,        sm + 16384 + soff);

#pragma unroll
  for (int ks = 0; ks < 16; ks++) {
    const int cur = ks & 1;
    if (ks < 15) {                         // issue next-tile loads first
      const char* wsrc = wcB + (ks + 1) * 8192;
      const char* xsrc = xcB + (ks + 1) * 4096;
      char* wd = sm + (cur ^ 1) * 8192;
      char* xd = sm + 16384 + (cur ^ 1) * 4096;
      gload16(wsrc + soff,        wd + soff);
      gload16(wsrc + soff + 4096, wd + soff + 4096);
      gload16(xsrc + soff,        xd + soff);
      asm volatile("s_waitcnt vmcnt(3)" ::: "memory");  // cur tile landed
    } else {
      asm volatile("s_waitcnt vmcnt(0)" ::: "memory");
    }
    __builtin_amdgcn_s_barrier();          // all waves' cur-tile loads landed
    asm volatile("" ::: "memory");
    const char* wbc = sm + cur * 8192;
    const char* xbc = sm + 16384 + cur * 4096;
    bf16x8 af[2], bfr[4];
#pragma unroll
    for (int mi = 0; mi < 2; mi++)
      af[mi] = *(const bf16x8*)(wbc + w * 2048 + mi * 1024 + lm * 64 + ((quad * 16) ^ xorq));
#pragma unroll
    for (int nt = 0; nt < 4; nt++)
      bfr[nt] = *(const bf16x8*)(xbc + nt * 1024 + lm * 64 + ((quad * 16) ^ xorq));
#pragma unroll
    for (int mi = 0; mi < 2; mi++)
#pragma unroll
      for (int nt = 0; nt < 4; nt++)
        acc[mi][nt] = __builtin_amdgcn_mfma_f32_16x16x32_bf16(af[mi], bfr[nt], acc[mi][nt], 0, 0, 0);
    asm volatile("s_waitcnt lgkmcnt(0)" ::: "memory");   // reads done pre-barrier
    __builtin_amdgcn_s_barrier();          // safe to overwrite cur^1 next iter
  }

  // ---- BN + ReLU -> hsB (bf16); C/D layout: col=lane&15, row=quad*4+reg ----
#pragma unroll
  for (int mi = 0; mi < 2; mi++)
#pragma unroll
    for (int nt = 0; nt < 4; nt++)
#pragma unroll
      for (int r = 0; r < 4; r++) {
        int o_loc = w * 32 + mi * 16 + quad * 4 + r;
        int l     = nt * 16 + lm;
        float v = acc[mi][nt][r] * bnA[o_loc] + bnC[o_loc];
        hsB[o_loc * 88 + l] = f2bfu(v > 0.f ? v : 0.f);
      }
  __syncthreads();

  // ---- stage B: out[b][mod*32+kk][o] = relu(hs @ lw^T + lb), via MFMA ----
  const int npass = img ? 1 : 2;
  const int nkt   = img ? 2 : 1;
  for (int p = 0; p < npass; p++) {
    f32x4 c2[2][2];
#pragma unroll
    for (int mi = 0; mi < 2; mi++)
#pragma unroll
      for (int nt2 = 0; nt2 < 2; nt2++) c2[mi][nt2] = (f32x4){0.f, 0.f, 0.f, 0.f};
    for (int kt = 0; kt < nkt; kt++) {
      int aoff = img ? kt * 32 : p * 32;
      int boff = img ? kt * 32 : 0;
      bf16x8 a2[2], b2[2];
#pragma unroll
      for (int mi = 0; mi < 2; mi++)
        a2[mi] = *(const bf16x8*)&hsB[(w * 32 + mi * 16 + lm) * 88 + aoff + quad * 8];
#pragma unroll
      for (int nt2 = 0; nt2 < 2; nt2++)
        b2[nt2] = *(const bf16x8*)&lw2[(nt2 * 16 + lm) * 72 + boff + quad * 8];
#pragma unroll
      for (int mi = 0; mi < 2; mi++)
#pragma unroll
        for (int nt2 = 0; nt2 < 2; nt2++)
          c2[mi][nt2] = __builtin_amdgcn_mfma_f32_16x16x32_bf16(a2[mi], b2[nt2], c2[mi][nt2], 0, 0, 0);
    }
#pragma unroll
    for (int mi = 0; mi < 2; mi++)
#pragma unroll
      for (int nt2 = 0; nt2 < 2; nt2++)
#pragma unroll
        for (int r = 0; r < 4; r++) {
          int kk    = nt2 * 16 + lm;
          int o_loc = w * 32 + mi * 16 + quad * 4 + r;
          float v = c2[mi][nt2][r] + lbs[kk];
          Cb[kk * 132 + o_loc] = v > 0.f ? v : 0.f;
        }
    __syncthreads();
    int b_out = img ? bidx : (bg * 2 + p);
    for (int i = tid; i < 4096; i += 256) {
      int kk = i >> 7, j = i & 127;
      out[((size_t)b_out * 128 + mod * 32 + kk) * 512 + ot * 128 + j] = Cb[kk * 132 + j];
    }
    if (p + 1 < npass) __syncthreads();
  }
}

// ======================================================================
// Fallback path (used only if workspace is too small): previous verified
// kernels, byte-for-byte behavior.
// ======================================================================
#define WB_OFF   0
#define XB_OFF   8192
#define CB_OFF   0
#define HS_OFF   16896
#define LW2_OFF  39424
#define BNA_OFF  44032
#define BNC_OFF  44544
#define LBS_OFF  45056
#define SMEM_SZ  45184

__global__ __launch_bounds__(256) void branch_kernel(
    const float* __restrict__ x0p, const float* __restrict__ x1p,
    const float* __restrict__ x2p, const float* __restrict__ x3p,
    const float* __restrict__ conv_w, const float* __restrict__ conv_b,
    const float* __restrict__ bn_g, const float* __restrict__ bn_b,
    const float* __restrict__ bn_m, const float* __restrict__ bn_v,
    const float* __restrict__ lin_w_img, const float* __restrict__ lin_b_img,
    const float* __restrict__ lin_w_pc, const float* __restrict__ lin_b_pc,
    float* __restrict__ out)
{
  __shared__ __align__(16) char sm[SMEM_SZ];
  u16*   Wb  = (u16*)(sm + WB_OFF);
  u16*   Xb  = (u16*)(sm + XB_OFF);
  float* Cb  = (float*)(sm + CB_OFF);
  u16*   hsB = (u16*)(sm + HS_OFF);
  u16*   lw2 = (u16*)(sm + LW2_OFF);
  float* bnA = (float*)(sm + BNA_OFF);
  float* bnC = (float*)(sm + BNC_OFF);
  float* lbs = (float*)(sm + LBS_OFF);

  const int ot  = blockIdx.x;
  const int tid = threadIdx.x;
  int y = blockIdx.y;
  int mod, bidx = 0, bg = 0;
  if      (y < 256) { mod = 0; bidx = y; }
  else if (y < 512) { mod = 1; bidx = y - 256; }
  else if (y < 640) { mod = 2; bg   = y - 512; }
  else              { mod = 3; bg   = y - 640; }
  const bool img = (mod < 2);
  const int  L   = img ? 49 : 32;
  const float* xp = (mod == 0) ? x0p : (mod == 1) ? x1p : (mod == 2) ? x2p : x3p;
  const float* lw = img ? (lin_w_img + mod * 32 * 49) : (lin_w_pc + (mod - 2) * 32 * 32);
  const float* lb = img ? (lin_b_img + mod * 32)      : (lin_b_pc + (mod - 2) * 32);

  for (int i = tid; i < 32 * 64; i += 256) {
    int kk = i >> 6, l = i & 63;
    float v = (l < L) ? lw[kk * L + l] : 0.f;
    lw2[kk * 72 + l] = f2bfu(v);
  }
  if (tid < 32) lbs[tid] = lb[tid];
  if (tid < 128) {
    int o = mod * 512 + ot * 128 + tid;
    float sc = bn_g[o] / sqrtf(bn_v[o] + 1e-5f);
    bnA[tid] = sc;
    bnC[tid] = (conv_b[o] - bn_m[o]) * sc + bn_b[o];
  }

  const int lane = tid & 63, w = tid >> 6, quad = lane >> 4, lm = lane & 15;
  const float* wbase = conv_w + (size_t)(mod * 512 + ot * 128) * 512;

  f32x4 acc[2][4];
#pragma unroll
  for (int mi = 0; mi < 2; mi++)
#pragma unroll
    for (int nt = 0; nt < 4; nt++) acc[mi][nt] = (f32x4){0.f, 0.f, 0.f, 0.f};

  for (int ks = 0; ks < 16; ks++) {
    int k0 = ks * 32;
    __syncthreads();
    for (int i = tid; i < 1024; i += 256) {
      int row = i >> 3, seg = i & 7;
      float4 v = *(const float4*)(wbase + (size_t)row * 512 + k0 + seg * 4);
      u16* d = &Wb[row * 32 + seg * 4];
      d[0] = f2bfu(v.x); d[1] = f2bfu(v.y); d[2] = f2bfu(v.z); d[3] = f2bfu(v.w);
    }
    for (int i = tid; i < 512; i += 256) {
      int l = i >> 3, seg = i & 7;
      float4 v = make_float4(0.f, 0.f, 0.f, 0.f);
      if (img) {
        if (l < 49) v = *(const float4*)(xp + (size_t)(bidx * 49 + l) * 512 + k0 + seg * 4);
      } else {
        v = *(const float4*)(xp + (size_t)(bg * 64 + l) * 512 + k0 + seg * 4);
      }
      u16* d = &Xb[l * 32 + seg * 4];
      d[0] = f2bfu(v.x); d[1] = f2bfu(v.y); d[2] = f2bfu(v.z); d[3] = f2bfu(v.w);
    }
    __syncthreads();
    bf16x8 af[2], bfr[4];
#pragma unroll
    for (int mi = 0; mi < 2; mi++)
      af[mi] = *(const bf16x8*)&Wb[(w * 32 + mi * 16 + lm) * 32 + quad * 8];
#pragma unroll
    for (int nt = 0; nt < 4; nt++)
      bfr[nt] = *(const bf16x8*)&Xb[(nt * 16 + lm) * 32 + quad * 8];
#pragma unroll
    for (int mi = 0; mi < 2; mi++)
#pragma unroll
      for (int nt = 0; nt < 4; nt++)
        acc[mi][nt] = __builtin_amdgcn_mfma_f32_16x16x32_bf16(af[mi], bfr[nt], acc[mi][nt], 0, 0, 0);
  }
  __syncthreads();

#pragma unroll
  for (int mi = 0; mi < 2; mi++)
#pragma unroll
    for (int nt = 0; nt < 4; nt++)
#pragma unroll
      for (int r = 0; r < 4; r++) {
        int o_loc = w * 32 + mi * 16 + quad * 4 + r;
        int l     = nt * 16 + lm;
        float v = acc[mi][nt][r] * bnA[o_loc] + bnC[o_loc];
        hsB[o_loc * 88 + l] = f2bfu(v > 0.f ? v : 0.f);
      }
  __syncthreads();

  const int npass = img ? 1 : 2;
  const int nkt   = img ? 2 : 1;
  for (int p = 0; p < npass; p++) {
    f32x4 c2[2][2];
#pragma unroll
    for (int mi = 0; mi < 2; mi++)
#pragma unroll
      for (int nt2 = 0; nt2 < 2; nt2++) c2[mi][nt2] = (f32x4){0.f, 0.f, 0.f, 0.f};
    for (int kt = 0; kt < nkt; kt++) {
      int aoff = img ? kt * 32 : p * 32;
      int boff = img ? kt * 32 : 0;
      bf16x8 a2[2], b2[2];
#pragma unroll
      for (int mi = 0; mi < 2; mi++)
        a2[mi] = *(const bf16x8*)&hsB[(w * 32 + mi * 16 + lm) * 88 + aoff + quad * 8];
#pragma unroll
      for (int nt2 = 0; nt2 < 2; nt2++)
        b2[nt2] = *(const bf16x8*)&lw2[(nt2 * 16 + lm) * 72 + boff + quad * 8];
#pragma unroll
      for (int mi = 0; mi < 2; mi++)
#pragma unroll
        for (int nt2 = 0; nt2 < 2; nt2++)
          c2[mi][nt2] = __builtin_amdgcn_mfma_f32_16x16x32_bf16(a2[mi], b2[nt2], c2[mi][nt2], 0, 0, 0);
    }
#pragma unroll
    for (int mi = 0; mi < 2; mi++)
#pragma unroll
      for (int nt2 = 0; nt2 < 2; nt2++)
#pragma unroll
        for (int r = 0; r < 4; r++) {
          int kk    = nt2 * 16 + lm;
          int o_loc = w * 32 + mi * 16 + quad * 4 + r;
          float v = c2[mi][nt2][r] + lbs[kk];
          Cb[kk * 132 + o_loc] = v > 0.f ? v : 0.f;
        }
    __syncthreads();
    int b_out = img ? bidx : (bg * 2 + p);
    for (int i = tid; i < 4096; i += 256) {
      int kk = i >> 7, j = i & 127;
      out[((size_t)b_out * 128 + mod * 32 + kk) * 512 + ot * 128 + j] = Cb[kk * 132 + j];
    }
    if (p + 1 < npass) __syncthreads();
  }
}

__global__ __launch_bounds__(256) void fps_kernel(const float* __restrict__ pts,
                                                  int* __restrict__ idx_out)
{
  __shared__ float xs[4096], ys[4096], zs[4096];
  __shared__ float rv[4];
  __shared__ int   ri[4];
  __shared__ int   far_sh;
  const int b = blockIdx.x, tid = threadIdx.x;
  const float* pb = pts + (size_t)b * 4096 * 3;

  for (int i = tid; i < 12288; i += 256) {
    float v = pb[i];
    int n = i / 3, c = i - n * 3;
    float* dst = (c == 0) ? xs : (c == 1) ? ys : zs;
    dst[n] = v;
  }
  float dreg[16];
#pragma unroll
  for (int i = 0; i < 16; i++) dreg[i] = 1e10f;
  __syncthreads();

  uint2 k2 = threefry2x32(0u, 42u, 0u, 1u);
  uint2 r  = threefry2x32(k2.x, k2.y, 0u, (u32)b);
  int far  = (int)((r.x ^ r.y) & 4095u);

  for (int s = 0; s < 128; s++) {
    if (tid == 0) idx_out[b * 128 + s] = far;
    float cx = xs[far], cy = ys[far], cz = zs[far];
    float bestv = -1.f; int besti = 0x7FFFFFFF;
#pragma unroll
    for (int i = 0; i < 16; i++) {
      int n = tid + (i << 8);
      float dx = __fsub_rn(xs[n], cx);
      float dy = __fsub_rn(ys[n], cy);
      float dz = __fsub_rn(zs[n], cz);
      float d  = __fadd_rn(__fadd_rn(__fmul_rn(dx, dx), __fmul_rn(dy, dy)), __fmul_rn(dz, dz));
      float nd = fminf(dreg[i], d);
      dreg[i] = nd;
      if (nd > bestv) { bestv = nd; besti = n; }
    }
#pragma unroll
    for (int off = 1; off < 64; off <<= 1) {
      float ov = __shfl_xor(bestv, off, 64);
      int   oi = __shfl_xor(besti, off, 64);
      if (ov > bestv || (ov == bestv && oi < besti)) { bestv = ov; besti = oi; }
    }
    if ((tid & 63) == 0) { rv[tid >> 6] = bestv; ri[tid >> 6] = besti; }
    __syncthreads();
    if (tid == 0) {
      float bv = rv[0]; int bi = ri[0];
#pragma unroll
      for (int w = 1; w < 4; w++)
        if (rv[w] > bv || (rv[w] == bv && ri[w] < bi)) { bv = rv[w]; bi = ri[w]; }
      far_sh = bi;
    }
    __syncthreads();
    far = far_sh;
  }
}

// ======================================================================
// Kernel 3: pos-enc MLP — 64x64 tile (4o x 4s per thread), BN1 hoisted
// ======================================================================
__global__ __launch_bounds__(256) void pe_kernel(
    const float* __restrict__ pts, const int* __restrict__ fps_idx,
    const float* __restrict__ w1, const float* __restrict__ b1,
    const float* __restrict__ g1, const float* __restrict__ bb1,
    const float* __restrict__ m1, const float* __restrict__ v1,
    const float* __restrict__ w2, const float* __restrict__ b2,
    const float* __restrict__ g2, const float* __restrict__ bb2,
    const float* __restrict__ m2, const float* __restrict__ v2,
    float* __restrict__ out)
{
  __shared__ float h1T[64][132];   // [s_local][c]
  __shared__ float w2s[64][132];   // [o_local][c]
  __shared__ float sc1s[128], C1s[128];
  const int ot = blockIdx.x;       // o tile (64 wide), 0..7
  const int st = blockIdx.y;       // s tile (64 wide), 0..1
  const int b  = blockIdx.z;
  const int tid = threadIdx.x;

  for (int i = tid; i < 64 * 32; i += 256) {
    int o = i >> 5, j = i & 31;
    float4 v = *(const float4*)(w2 + (size_t)(ot * 64 + o) * 128 + j * 4);
    *(float4*)&w2s[o][j * 4] = v;
  }
  if (tid < 128) {
    float sc = g1[tid] / sqrtf(v1[tid] + 1e-5f);
    sc1s[tid] = sc;
    C1s[tid]  = (b1[tid] - m1[tid]) * sc + bb1[tid];
  }
  __syncthreads();

  {
    int s_l = tid & 63;
    int cq  = tid >> 6;
    int s   = st * 64 + s_l;
    int n   = fps_idx[b * 128 + s];
    float px = pts[((size_t)b * 4096 + n) * 3 + 0];
    float py = pts[((size_t)b * 4096 + n) * 3 + 1];
    float pz = pts[((size_t)b * 4096 + n) * 3 + 2];
    for (int cc = 0; cc < 32; cc++) {
      int c = cq * 32 + cc;
      float d  = fmaf(pz, w1[c * 3 + 2], fmaf(py, w1[c * 3 + 1], px * w1[c * 3]));
      float h  = d * sc1s[c] + C1s[c];
      h1T[s_l][c] = h > 0.f ? h : 0.f;
    }
  }
  __syncthreads();

  const int tx = tid & 15, ty = tid >> 4;
  float acc[4][4];
#pragma unroll
  for (int j = 0; j < 4; j++)
#pragma unroll
    for (int i = 0; i < 4; i++) acc[j][i] = 0.f;

  for (int c = 0; c < 128; c += 4) {
    float4 wv[4];
#pragma unroll
    for (int j = 0; j < 4; j++) wv[j] = *(const float4*)&w2s[tx + 16 * j][c];
#pragma unroll
    for (int si = 0; si < 4; si++) {
      float4 hv = *(const float4*)&h1T[ty + 16 * si][c];
#pragma unroll
      for (int j = 0; j < 4; j++) {
        acc[j][si] = fmaf(hv.x, wv[j].x, acc[j][si]);
        acc[j][si] = fmaf(hv.y, wv[j].y, acc[j][si]);
        acc[j][si] = fmaf(hv.z, wv[j].z, acc[j][si]);
        acc[j][si] = fmaf(hv.w, wv[j].w, acc[j][si]);
      }
    }
  }

#pragma unroll
  for (int j = 0; j < 4; j++) {
    int o = ot * 64 + tx + 16 * j;
    float sc = g2[o] / sqrtf(v2[o] + 1e-5f);
    float C  = (b2[o] - m2[o]) * sc + bb2[o];
#pragma unroll
    for (int si = 0; si < 4; si++) {
      int s = st * 64 + ty + 16 * si;
      float v = acc[j][si] * sc + C;
      v = v > 0.f ? v : 0.f;
      size_t oi = ((size_t)b * 128 + s) * 512 + o;
      out[oi] = out[oi] + v;
    }
  }
}

// ======================================================================
extern "C" void kernel_launch(void* const* d_in, const int* in_sizes, int n_in,
                              void* d_out, int out_size, void* d_ws, size_t ws_size,
                              hipStream_t stream) {
  const float* rgb    = (const float*)d_in[0];
  const float* depth  = (const float*)d_in[1];
  const float* mmwave = (const float*)d_in[2];
  const float* lidar  = (const float*)d_in[3];
  const float* pts    = (const float*)d_in[4];
  const float* conv_w = (const float*)d_in[5];
  const float* conv_b = (const float*)d_in[6];
  const float* bn_g   = (const float*)d_in[7];
  const float* bn_b   = (const float*)d_in[8];
  const float* bn_m   = (const float*)d_in[9];
  const float* bn_v   = (const float*)d_in[10];
  const float* lwi    = (const float*)d_in[11];
  const float* lbi    = (const float*)d_in[12];
  const float* lwp    = (const float*)d_in[13];
  const float* lbp    = (const float*)d_in[14];
  const float* pw1    = (const float*)d_in[15];
  const float* pb1    = (const float*)d_in[16];
  const float* pg1    = (const float*)d_in[17];
  const float* pbb1   = (const float*)d_in[18];
  const float* pm1    = (const float*)d_in[19];
  const float* pv1    = (const float*)d_in[20];
  const float* pw2    = (const float*)d_in[21];
  const float* pb2    = (const float*)d_in[22];
  const float* pg2    = (const float*)d_in[23];
  const float* pbb2   = (const float*)d_in[24];
  const float* pm2    = (const float*)d_in[25];
  const float* pv2    = (const float*)d_in[26];
  float* out = (float*)d_out;
  int* fps_idx = (int*)d_ws;                       // [0, 131072)

  // ws layout: fps_idx 128KB | Wc 2MB bf16 | Xc 48MB bf16
  const size_t NEED = 131072 + 2097152 + (size_t)768 * 65536;  // 52,559,872
  if (ws_size >= NEED) {
    u16* Wc = (u16*)((char*)d_ws + 131072);
    u16* Xc = (u16*)((char*)d_ws + 2228224);
    convert_kernel<<<dim3(12800), 256, 0, stream>>>(rgb, depth, mmwave, lidar,
        conv_w, Wc, Xc);
    fused_kernel<<<dim3(3328), 256, 0, stream>>>(pts, fps_idx, Wc, Xc,
        conv_b, bn_g, bn_b, bn_m, bn_v, lwi, lbi, lwp, lbp, out);
  } else {
    branch_kernel<<<dim3(4, 768), 256, 0, stream>>>(rgb, depth, mmwave, lidar,
        conv_w, conv_b, bn_g, bn_b, bn_m, bn_v, lwi, lbi, lwp, lbp, out);
    fps_kernel<<<dim3(256), 256, 0, stream>>>(pts, fps_idx);
  }
  pe_kernel<<<dim3(8, 2, 256), 256, 0, stream>>>(pts, fps_idx, pw1, pb1, pg1, pbb1, pm1, pv1,
      pw2, pb2, pg2, pbb2, pm2, pv2, out);
}

// Round 3
// 430.028 us; speedup vs baseline: 1.7103x; 1.0342x over previous
//
#include <hip/hip_runtime.h>
#include <stdint.h>

typedef unsigned int u32;
typedef unsigned short u16;

typedef __attribute__((ext_vector_type(8))) short bf16x8;
typedef __attribute__((ext_vector_type(8))) unsigned short u16x8;
typedef __attribute__((ext_vector_type(4))) float f32x4;

// f32 -> bf16 round-to-nearest-even
__device__ __forceinline__ u16 f2bfu(float f) {
  union { float f; u32 u; } v; v.f = f;
  return (u16)((v.u + 0x7FFFu + ((v.u >> 16) & 1u)) >> 16);
}
__device__ __forceinline__ float bf2f(u16 h) {
  union { u32 u; float f; } v; v.u = ((u32)h) << 16;
  return v.f;
}

// async global->LDS, 16B per lane; lds ptr must be base + lane*16 (linear)
__device__ __forceinline__ void gload16(const void* g, void* l) {
  __builtin_amdgcn_global_load_lds(
      (const __attribute__((address_space(1))) void*)g,
      (__attribute__((address_space(3))) void*)l, 16, 0, 0);
}

// DPP-based argmax merge step (VALU-speed cross-lane, no LDS pipe).
// bound_ctrl=false keeps OLD value in invalid lanes -> self-merge (no-op).
template <int CTRL>
__device__ __forceinline__ void dpp_merge(float& bv, int& bi) {
  int ovi = __builtin_amdgcn_update_dpp(__float_as_int(bv), __float_as_int(bv),
                                        CTRL, 0xF, 0xF, false);
  int oii = __builtin_amdgcn_update_dpp(bi, bi, CTRL, 0xF, 0xF, false);
  float ov = __int_as_float(ovi);
  if (ov > bv || (ov == bv && oii < bi)) { bv = ov; bi = oii; }
}

// ---------- Threefry-2x32/20 (JAX PRNG) ----------
__device__ __forceinline__ u32 rotl32(u32 x, int r) { return (x << r) | (x >> (32 - r)); }

__device__ __forceinline__ uint2 threefry2x32(u32 k0, u32 k1, u32 x0, u32 x1) {
  u32 ks2 = k0 ^ k1 ^ 0x1BD11BDAu;
  x0 += k0; x1 += k1;
#define TF_G(a,b,c,d) { x0 += x1; x1 = rotl32(x1,a); x1 ^= x0; \
                        x0 += x1; x1 = rotl32(x1,b); x1 ^= x0; \
                        x0 += x1; x1 = rotl32(x1,c); x1 ^= x0; \
                        x0 += x1; x1 = rotl32(x1,d); x1 ^= x0; }
  TF_G(13,15,26,6);  x0 += k1;  x1 += ks2 + 1u;
  TF_G(17,29,16,24); x0 += ks2; x1 += k0  + 2u;
  TF_G(13,15,26,6);  x0 += k0;  x1 += k1  + 3u;
  TF_G(17,29,16,24); x0 += k1;  x1 += ks2 + 4u;
  TF_G(13,15,26,6);  x0 += ks2; x1 += k0  + 5u;
#undef TF_G
  return make_uint2(x0, x1);
}

// ======================================================================
// Kernel 0: one-pass bf16 pre-convert of X (k-tiled, padded, pre-swizzled),
// W (k-tiled per (mod,ot), pre-swizzled), pe W2 hi/lo split, and pe BN
// constant tables.
// ======================================================================
__global__ __launch_bounds__(256) void convert_kernel(
    const float* __restrict__ rgb, const float* __restrict__ depth,
    const float* __restrict__ mmw, const float* __restrict__ lid,
    const float* __restrict__ conv_w, u16* __restrict__ Wc, u16* __restrict__ Xc,
    const float* __restrict__ pw2,
    const float* __restrict__ pg1, const float* __restrict__ pbb1,
    const float* __restrict__ pm1, const float* __restrict__ pv1,
    const float* __restrict__ pb1,
    const float* __restrict__ pg2, const float* __restrict__ pbb2,
    const float* __restrict__ pm2, const float* __restrict__ pv2,
    const float* __restrict__ pb2,
    u16* __restrict__ W2h, u16* __restrict__ W2l,
    float* __restrict__ sc1C1, float* __restrict__ sc2C2)
{
  const int bid = blockIdx.x, tid = threadIdx.x;
  if (bid < 12288) {                       // X part: (slot y, ks) per block
    float4 v0 = make_float4(0.f, 0.f, 0.f, 0.f), v1 = v0;
    const int y = bid >> 4, ks = bid & 15;
    const int l = tid >> 2, seg = tid & 3;
    const float* xp; size_t row = 0; bool valid = true;
    if (y < 256)      { xp = rgb;   row = (size_t)y * 49 + l;         valid = (l < 49); }
    else if (y < 512) { xp = depth; row = (size_t)(y - 256) * 49 + l; valid = (l < 49); }
    else if (y < 640) { xp = mmw;   row = (size_t)(y - 512) * 64 + l; }
    else              { xp = lid;   row = (size_t)(y - 640) * 64 + l; }
    if (valid) {
      const float* s = xp + row * 512 + ks * 32 + seg * 8;
      v0 = *(const float4*)s; v1 = *(const float4*)(s + 4);
    }
    char* dst = (char*)Xc + (size_t)y * 65536 + ks * 4096 + l * 64 + ((seg ^ ((l >> 1) & 3)) << 4);
    u16x8 pk;
    pk[0] = f2bfu(v0.x); pk[1] = f2bfu(v0.y); pk[2] = f2bfu(v0.z); pk[3] = f2bfu(v0.w);
    pk[4] = f2bfu(v1.x); pk[5] = f2bfu(v1.y); pk[6] = f2bfu(v1.z); pk[7] = f2bfu(v1.w);
    *(u16x8*)dst = pk;
  } else if (bid < 12800) {                // W part: 2 blocks per 8KB tile
    const int t = bid - 12288;             // 0..511
    const int tile = t >> 1, half = t & 1; // tile = (mod*4+ot)*16+ks
    const int row = (tid >> 2) + half * 64, seg = tid & 3;
    const float* s = conv_w + (size_t)((tile >> 4) * 128 + row) * 512 + (tile & 15) * 32 + seg * 8;
    float4 v0 = *(const float4*)s; float4 v1 = *(const float4*)(s + 4);
    char* dst = (char*)Wc + (size_t)tile * 8192 + row * 64 + ((seg ^ ((row >> 1) & 3)) << 4);
    u16x8 pk;
    pk[0] = f2bfu(v0.x); pk[1] = f2bfu(v0.y); pk[2] = f2bfu(v0.z); pk[3] = f2bfu(v0.w);
    pk[4] = f2bfu(v1.x); pk[5] = f2bfu(v1.y); pk[6] = f2bfu(v1.z); pk[7] = f2bfu(v1.w);
    *(u16x8*)dst = pk;
  } else if (bid < 12832) {                // pe W2 hi/lo split
    const int idx = (bid - 12800) * 2048 + tid * 8;   // element index, 8 per thread
    const float* s = pw2 + idx;
    float4 v0 = *(const float4*)s; float4 v1 = *(const float4*)(s + 4);
    float vv[8] = {v0.x, v0.y, v0.z, v0.w, v1.x, v1.y, v1.z, v1.w};
    u16x8 hh, hl;
#pragma unroll
    for (int j = 0; j < 8; j++) {
      u16 hi = f2bfu(vv[j]);
      hh[j] = hi;
      hl[j] = f2bfu(vv[j] - bf2f(hi));
    }
    *(u16x8*)(W2h + idx) = hh;
    *(u16x8*)(W2l + idx) = hl;
  } else {                                 // pe BN constant tables
    if (tid < 128) {
      float sc = pg1[tid] / sqrtf(pv1[tid] + 1e-5f);
      sc1C1[tid]       = sc;
      sc1C1[128 + tid] = (pb1[tid] - pm1[tid]) * sc + pbb1[tid];
    }
    for (int o = tid; o < 512; o += 256) {
      float sc = pg2[o] / sqrtf(pv2[o] + 1e-5f);
      sc2C2[o]       = sc;
      sc2C2[512 + o] = (pb2[o] - pm2[o]) * sc + pbb2[o];
    }
  }
}

// ======================================================================
// Kernel 1 (fused): blocks 0..255 = FPS (register points, tree argmax,
// DPP wave-reduce, 1 barrier/step); blocks 256+ = branch conv via bf16
// MFMA with global_load_lds 2-phase pipeline.
// ======================================================================
#define FSMEM_SZ 52864

__global__ __launch_bounds__(256) void fused_kernel(
    const float* __restrict__ pts, int* __restrict__ fps_idx,
    const u16* __restrict__ Wc, const u16* __restrict__ Xc,
    const float* __restrict__ conv_b,
    const float* __restrict__ bn_g, const float* __restrict__ bn_b,
    const float* __restrict__ bn_m, const float* __restrict__ bn_v,
    const float* __restrict__ lin_w_img, const float* __restrict__ lin_b_img,
    const float* __restrict__ lin_w_pc, const float* __restrict__ lin_b_pc,
    float* __restrict__ out)
{
  __shared__ __align__(16) char sm[FSMEM_SZ];
  const int tid = threadIdx.x;

  if (blockIdx.x < 256) {
    // ---------------- FPS (bit-exact results, faster chain) ----------------
    float* xs = (float*)sm;
    float* ys = (float*)(sm + 16384);
    float* zs = (float*)(sm + 32768);
    float* rv2 = (float*)(sm + 49152);   // [2][4]
    int*   ri2 = (int*)(sm + 49184);     // [2][4]
    const int b = blockIdx.x;
    const float* pb = pts + (size_t)b * 4096 * 3;

    __builtin_amdgcn_s_setprio(1);       // FPS chain is the block-critical path

    for (int i = tid; i < 12288; i += 256) {
      float v = pb[i];
      int n = i / 3, c = i - n * 3;
      float* dstp = (c == 0) ? xs : (c == 1) ? ys : zs;
      dstp[n] = v;
    }
    __syncthreads();

    // own 16 points in registers
    float xr[16], yr[16], zr[16], dreg[16];
#pragma unroll
    for (int i = 0; i < 16; i++) {
      int n = tid + (i << 8);
      xr[i] = xs[n]; yr[i] = ys[n]; zr[i] = zs[n];
      dreg[i] = 1e10f;
    }

    uint2 k2 = threefry2x32(0u, 42u, 0u, 1u);
    uint2 r  = threefry2x32(k2.x, k2.y, 0u, (u32)b);
    int far  = (int)((r.x ^ r.y) & 4095u);
    const int wv = tid >> 6;

    for (int s = 0; s < 128; s++) {
      if (tid == 0) fps_idx[b * 128 + s] = far;
      float cx = xs[far], cy = ys[far], cz = zs[far];
      float bv[16]; int bn[16];
#pragma unroll
      for (int i = 0; i < 16; i++) {
        float dx = __fsub_rn(xr[i], cx);
        float dy = __fsub_rn(yr[i], cy);
        float dz = __fsub_rn(zr[i], cz);
        float d  = __fadd_rn(__fadd_rn(__fmul_rn(dx, dx), __fmul_rn(dy, dy)), __fmul_rn(dz, dz));
        float nd = fminf(dreg[i], d);
        dreg[i] = nd;
        bv[i] = nd; bn[i] = tid + (i << 8);
      }
      // tree argmax over 16 local points; local indices ascend with i, so a
      // tie must keep the lower slot -> strict > is exactly the serial rule.
#define MRG(i, j) if (bv[j] > bv[i]) { bv[i] = bv[j]; bn[i] = bn[j]; }
      MRG(0, 8)  MRG(1, 9)  MRG(2, 10) MRG(3, 11)
      MRG(4, 12) MRG(5, 13) MRG(6, 14) MRG(7, 15)
      MRG(0, 4)  MRG(1, 5)  MRG(2, 6)  MRG(3, 7)
      MRG(0, 2)  MRG(1, 3)
      MRG(0, 1)
#undef MRG
      float bestv = bv[0]; int besti = bn[0];
      // wave argmax via DPP (VALU pipe): row_shr 1/2/4/8 + bcast15/31 -> lane63
      dpp_merge<0x111>(bestv, besti);
      dpp_merge<0x112>(bestv, besti);
      dpp_merge<0x114>(bestv, besti);
      dpp_merge<0x118>(bestv, besti);
      dpp_merge<0x142>(bestv, besti);
      dpp_merge<0x143>(bestv, besti);
      float wbv = __int_as_float(__builtin_amdgcn_readlane(__float_as_int(bestv), 63));
      int   wbi = __builtin_amdgcn_readlane(besti, 63);

      const int par = s & 1;
      if ((tid & 63) == 0) { rv2[par * 4 + wv] = wbv; ri2[par * 4 + wv] = wbi; }
      __syncthreads();
      // all threads merge the 4 wave results redundantly (uniform result)
      float bvv = rv2[par * 4]; int bii = ri2[par * 4];
#pragma unroll
      for (int w2 = 1; w2 < 4; w2++) {
        float wvv = rv2[par * 4 + w2]; int wii = ri2[par * 4 + w2];
        if (wvv > bvv || (wvv == bvv && wii < bii)) { bvv = wvv; bii = wii; }
      }
      far = bii;
    }
    return;
  }

  // ---------------- branch GEMM path ----------------
  const int g  = (int)blockIdx.x - 256;
  const int ot = g & 3;
  const int y  = g >> 2;
  int mod, bidx = 0, bg = 0;
  if      (y < 256) { mod = 0; bidx = y; }
  else if (y < 512) { mod = 1; bidx = y - 256; }
  else if (y < 640) { mod = 2; bg   = y - 512; }
  else              { mod = 3; bg   = y - 640; }
  const bool img = (mod < 2);
  const int  L   = img ? 49 : 32;
  const float* lw = img ? (lin_w_img + mod * 32 * 49) : (lin_w_pc + (mod - 2) * 32 * 32);
  const float* lb = img ? (lin_b_img + mod * 32)      : (lin_b_pc + (mod - 2) * 32);

  u16*   lw2 = (u16*)(sm + 47104);
  float* bnA = (float*)(sm + 51712);
  float* bnC = (float*)(sm + 52224);
  float* lbs = (float*)(sm + 52736);
  u16*   hsB = (u16*)(sm + 24576);
  float* Cb  = (float*)sm;

  for (int i = tid; i < 32 * 64; i += 256) {
    int kk = i >> 6, l = i & 63;
    float v = (l < L) ? lw[kk * L + l] : 0.f;
    lw2[kk * 72 + l] = f2bfu(v);
  }
  if (tid < 32) lbs[tid] = lb[tid];
  if (tid < 128) {
    int o = mod * 512 + ot * 128 + tid;
    float sc = bn_g[o] / sqrtf(bn_v[o] + 1e-5f);
    bnA[tid] = sc;
    bnC[tid] = (conv_b[o] - bn_m[o]) * sc + bn_b[o];
  }

  const int lane = tid & 63, w = tid >> 6, quad = lane >> 4, lm = lane & 15;
  const int xorq = ((lm >> 1) & 3) << 4;     // read-side swizzle (matches convert)
  const int soff = w * 1024 + lane * 16;     // linear per-lane stage offset

  const char* wcB = (const char*)Wc + (size_t)(mod * 4 + ot) * (16 * 8192);
  const char* xcB = (const char*)Xc + (size_t)y * 65536;

  f32x4 acc[2][4];
#pragma unroll
  for (int mi = 0; mi < 2; mi++)
#pragma unroll
    for (int nt = 0; nt < 4; nt++) acc[mi][nt] = (f32x4){0.f, 0.f, 0.f, 0.f};

  // drain prologue loads so manual vmcnt counting is exact
  asm volatile("s_waitcnt vmcnt(0)" ::: "memory");
  // prologue: stage ks=0 into buffer 0 (3 gloads: 8KB W + 4KB X)
  gload16(wcB + soff,        sm + soff);
  gload16(wcB + soff + 4096, sm + soff + 4096);
  gload16(xcB + soff,        sm + 16384 + soff);

#pragma unroll
  for (int ks = 0; ks < 16; ks++) {
    const int cur = ks & 1;
    if (ks < 15) {                         // issue next-tile loads first
      const char* wsrc = wcB + (ks + 1) * 8192;
      const char* xsrc = xcB + (ks + 1) * 4096;
      char* wd = sm + (cur ^ 1) * 8192;
      char* xd = sm + 16384 + (cur ^ 1) * 4096;
      gload16(wsrc + soff,        wd + soff);
      gload16(wsrc + soff + 4096, wd + soff + 4096);
      gload16(xsrc + soff,        xd + soff);
      asm volatile("s_waitcnt vmcnt(3)" ::: "memory");  // cur tile landed
    } else {
      asm volatile("s_waitcnt vmcnt(0)" ::: "memory");
    }
    __builtin_amdgcn_s_barrier();          // all waves' cur-tile loads landed
    asm volatile("" ::: "memory");
    const char* wbc = sm + cur * 8192;
    const char* xbc = sm + 16384 + cur * 4096;
    bf16x8 af[2], bfr[4];
#pragma unroll
    for (int mi = 0; mi < 2; mi++)
      af[mi] = *(const bf16x8*)(wbc + w * 2048 + mi * 1024 + lm * 64 + ((quad * 16) ^ xorq));
#pragma unroll
    for (int nt = 0; nt < 4; nt++)
      bfr[nt] = *(const bf16x8*)(xbc + nt * 1024 + lm * 64 + ((quad * 16) ^ xorq));
#pragma unroll
    for (int mi = 0; mi < 2; mi++)
#pragma unroll
      for (int nt = 0; nt < 4; nt++)
        acc[mi][nt] = __builtin_amdgcn_mfma_f32_16x16x32_bf16(af[mi], bfr[nt], acc[mi][nt], 0, 0, 0);
    asm volatile("s_waitcnt lgkmcnt(0)" ::: "memory");   // reads done pre-barrier
    __builtin_amdgcn_s_barrier();          // safe to overwrite cur^1 next iter
  }

  // ---- BN + ReLU -> hsB (bf16); C/D layout: col=lane&15, row=quad*4+reg ----
#pragma unroll
  for (int mi = 0; mi < 2; mi++)
#pragma unroll
    for (int nt = 0; nt < 4; nt++)
#pragma unroll
      for (int r = 0; r < 4; r++) {
        int o_loc = w * 32 + mi * 16 + quad * 4 + r;
        int l     = nt * 16 + lm;
        float v = acc[mi][nt][r] * bnA[o_loc] + bnC[o_loc];
        hsB[o_loc * 88 + l] = f2bfu(v > 0.f ? v : 0.f);
      }
  __syncthreads();

  // ---- stage B: out[b][mod*32+kk][o] = relu(hs @ lw^T + lb), via MFMA ----
  const int npass = img ? 1 : 2;
  const int nkt   = img ? 2 : 1;
  for (int p = 0; p < npass; p++) {
    f32x4 c2[2][2];
#pragma unroll
    for (int mi = 0; mi < 2; mi++)
#pragma unroll
      for (int nt2 = 0; nt2 < 2; nt2++) c2[mi][nt2] = (f32x4){0.f, 0.f, 0.f, 0.f};
    for (int kt = 0; kt < nkt; kt++) {
      int aoff = img ? kt * 32 : p * 32;
      int boff = img ? kt * 32 : 0;
      bf16x8 a2[2], b2[2];
#pragma unroll
      for (int mi = 0; mi < 2; mi++)
        a2[mi] = *(const bf16x8*)&hsB[(w * 32 + mi * 16 + lm) * 88 + aoff + quad * 8];
#pragma unroll
      for (int nt2 = 0; nt2 < 2; nt2++)
        b2[nt2] = *(const bf16x8*)&lw2[(nt2 * 16 + lm) * 72 + boff + quad * 8];
#pragma unroll
      for (int mi = 0; mi < 2; mi++)
#pragma unroll
        for (int nt2 = 0; nt2 < 2; nt2++)
          c2[mi][nt2] = __builtin_amdgcn_mfma_f32_16x16x32_bf16(a2[mi], b2[nt2], c2[mi][nt2], 0, 0, 0);
    }
#pragma unroll
    for (int mi = 0; mi < 2; mi++)
#pragma unroll
      for (int nt2 = 0; nt2 < 2; nt2++)
#pragma unroll
        for (int r = 0; r < 4; r++) {
          int kk    = nt2 * 16 + lm;
          int o_loc = w * 32 + mi * 16 + quad * 4 + r;
          float v = c2[mi][nt2][r] + lbs[kk];
          Cb[kk * 132 + o_loc] = v > 0.f ? v : 0.f;
        }
    __syncthreads();
    int b_out = img ? bidx : (bg * 2 + p);
    for (int i = tid; i < 4096; i += 256) {
      int kk = i >> 7, j = i & 127;
      out[((size_t)b_out * 128 + mod * 32 + kk) * 512 + ot * 128 + j] = Cb[kk * 132 + j];
    }
    if (p + 1 < npass) __syncthreads();
  }
}

// ======================================================================
// Kernel 2: pos-enc MLP via split-bf16 MFMA (hi+lo, 3 MFMA per tile).
// Tile: 64s x 64o, K=128. LDS exactly 64KB, XOR-granule swizzled.
// ======================================================================
__global__ __launch_bounds__(256) void pe_mfma_kernel(
    const float* __restrict__ pts, const int* __restrict__ fps_idx,
    const float* __restrict__ w1,
    const u16* __restrict__ W2h, const u16* __restrict__ W2l,
    const float* __restrict__ sc1C1, const float* __restrict__ sc2C2,
    float* __restrict__ out)
{
  __shared__ __align__(16) char sm[65536];
  u16* Ph = (u16*)sm;            // [64][128] u16, granule-swizzled
  u16* Pl = (u16*)(sm + 16384);
  u16* Wh = (u16*)(sm + 32768);
  u16* Wl = (u16*)(sm + 49152);
  const int ot = blockIdx.x;     // o tile (64 wide), 0..7
  const int st = blockIdx.y;     // s tile (64 wide), 0..1
  const int b  = blockIdx.z;
  const int tid = threadIdx.x;

  // --- stage W2 tile (hi/lo), granule-swizzled: 64 rows x 16 granules ---
  for (int i = tid; i < 1024; i += 256) {
    int o = i >> 4, gn = i & 15;
    u16x8 vh = *(const u16x8*)(W2h + ((size_t)(ot * 64 + o)) * 128 + gn * 8);
    u16x8 vl = *(const u16x8*)(W2l + ((size_t)(ot * 64 + o)) * 128 + gn * 8);
    int gg = gn ^ (o & 15);
    *(u16x8*)(Wh + o * 128 + gg * 8) = vh;
    *(u16x8*)(Wl + o * 128 + gg * 8) = vl;
  }
  // --- compute h1 (f32, same expr as before), split hi/lo, store swizzled ---
  {
    int s_l = tid >> 2;                  // 0..63
    int cq  = (tid & 3) * 32;            // this thread's 32 c's
    int s   = st * 64 + s_l;
    int n   = fps_idx[b * 128 + s];
    float px = pts[((size_t)b * 4096 + n) * 3 + 0];
    float py = pts[((size_t)b * 4096 + n) * 3 + 1];
    float pz = pts[((size_t)b * 4096 + n) * 3 + 2];
    for (int c0 = 0; c0 < 32; c0 += 8) {
      u16x8 hh, hl;
#pragma unroll
      for (int j = 0; j < 8; j++) {
        int c = cq + c0 + j;
        float d = fmaf(pz, w1[c * 3 + 2], fmaf(py, w1[c * 3 + 1], px * w1[c * 3]));
        float h = d * sc1C1[c] + sc1C1[128 + c];
        h = h > 0.f ? h : 0.f;
        u16 hi = f2bfu(h);
        hh[j] = hi;
        hl[j] = f2bfu(h - bf2f(hi));
      }
      int gn = (cq + c0) >> 3;
      int gg = gn ^ (s_l & 15);
      *(u16x8*)(Ph + s_l * 128 + gg * 8) = hh;
      *(u16x8*)(Pl + s_l * 128 + gg * 8) = hl;
    }
  }
  __syncthreads();

  // --- MFMA: wave w covers s [w*16, w*16+16) x o [0,64), K=128 ---
  const int lane = tid & 63, w = tid >> 6, quad = lane >> 4, lm = lane & 15;
  f32x4 acc[4];
#pragma unroll
  for (int nt = 0; nt < 4; nt++) acc[nt] = (f32x4){0.f, 0.f, 0.f, 0.f};

  const int arow = w * 16 + lm;
#pragma unroll
  for (int kt = 0; kt < 4; kt++) {
    int ag = ((kt * 4 + quad) ^ (arow & 15)) * 8;
    bf16x8 pah = *(const bf16x8*)(Ph + arow * 128 + ag);
    bf16x8 pal = *(const bf16x8*)(Pl + arow * 128 + ag);
#pragma unroll
    for (int nt = 0; nt < 4; nt++) {
      int brow = nt * 16 + lm;
      int bg = ((kt * 4 + quad) ^ (brow & 15)) * 8;
      bf16x8 wbh = *(const bf16x8*)(Wh + brow * 128 + bg);
      bf16x8 wbl = *(const bf16x8*)(Wl + brow * 128 + bg);
      acc[nt] = __builtin_amdgcn_mfma_f32_16x16x32_bf16(pah, wbh, acc[nt], 0, 0, 0);
      acc[nt] = __builtin_amdgcn_mfma_f32_16x16x32_bf16(pah, wbl, acc[nt], 0, 0, 0);
      acc[nt] = __builtin_amdgcn_mfma_f32_16x16x32_bf16(pal, wbh, acc[nt], 0, 0, 0);
    }
  }

  // --- epilogue: BN2 + ReLU + RMW out. C layout: col=lm, row=quad*4+r ---
#pragma unroll
  for (int nt = 0; nt < 4; nt++) {
    int o = ot * 64 + nt * 16 + lm;
    float sc = sc2C2[o], C = sc2C2[512 + o];
#pragma unroll
    for (int r = 0; r < 4; r++) {
      int s = st * 64 + w * 16 + quad * 4 + r;
      float v = acc[nt][r] * sc + C;
      v = v > 0.f ? v : 0.f;
      size_t oi = ((size_t)b * 128 + s) * 512 + o;
      out[oi] = out[oi] + v;
    }
  }
}

// ======================================================================
// Fallback path (used only if workspace is too small): previous verified
// kernels, byte-for-byte behavior.
// ======================================================================
#define WB_OFF   0
#define XB_OFF   8192
#define CB_OFF   0
#define HS_OFF   16896
#define LW2_OFF  39424
#define BNA_OFF  44032
#define BNC_OFF  44544
#define LBS_OFF  45056
#define SMEM_SZ  45184

__global__ __launch_bounds__(256) void branch_kernel(
    const float* __restrict__ x0p, const float* __restrict__ x1p,
    const float* __restrict__ x2p, const float* __restrict__ x3p,
    const float* __restrict__ conv_w, const float* __restrict__ conv_b,
    const float* __restrict__ bn_g, const float* __restrict__ bn_b,
    const float* __restrict__ bn_m, const float* __restrict__ bn_v,
    const float* __restrict__ lin_w_img, const float* __restrict__ lin_b_img,
    const float* __restrict__ lin_w_pc, const float* __restrict__ lin_b_pc,
    float* __restrict__ out)
{
  __shared__ __align__(16) char sm[SMEM_SZ];
  u16*   Wb  = (u16*)(sm + WB_OFF);
  u16*   Xb  = (u16*)(sm + XB_OFF);
  float* Cb  = (float*)(sm + CB_OFF);
  u16*   hsB = (u16*)(sm + HS_OFF);
  u16*   lw2 = (u16*)(sm + LW2_OFF);
  float* bnA = (float*)(sm + BNA_OFF);
  float* bnC = (float*)(sm + BNC_OFF);
  float* lbs = (float*)(sm + LBS_OFF);

  const int ot  = blockIdx.x;
  const int tid = threadIdx.x;
  int y = blockIdx.y;
  int mod, bidx = 0, bg = 0;
  if      (y < 256) { mod = 0; bidx = y; }
  else if (y < 512) { mod = 1; bidx = y - 256; }
  else if (y < 640) { mod = 2; bg   = y - 512; }
  else              { mod = 3; bg   = y - 640; }
  const bool img = (mod < 2);
  const int  L   = img ? 49 : 32;
  const float* xp = (mod == 0) ? x0p : (mod == 1) ? x1p : (mod == 2) ? x2p : x3p;
  const float* lw = img ? (lin_w_img + mod * 32 * 49) : (lin_w_pc + (mod - 2) * 32 * 32);
  const float* lb = img ? (lin_b_img + mod * 32)      : (lin_b_pc + (mod - 2) * 32);

  for (int i = tid; i < 32 * 64; i += 256) {
    int kk = i >> 6, l = i & 63;
    float v = (l < L) ? lw[kk * L + l] : 0.f;
    lw2[kk * 72 + l] = f2bfu(v);
  }
  if (tid < 32) lbs[tid] = lb[tid];
  if (tid < 128) {
    int o = mod * 512 + ot * 128 + tid;
    float sc = bn_g[o] / sqrtf(bn_v[o] + 1e-5f);
    bnA[tid] = sc;
    bnC[tid] = (conv_b[o] - bn_m[o]) * sc + bn_b[o];
  }

  const int lane = tid & 63, w = tid >> 6, quad = lane >> 4, lm = lane & 15;
  const float* wbase = conv_w + (size_t)(mod * 512 + ot * 128) * 512;

  f32x4 acc[2][4];
#pragma unroll
  for (int mi = 0; mi < 2; mi++)
#pragma unroll
    for (int nt = 0; nt < 4; nt++) acc[mi][nt] = (f32x4){0.f, 0.f, 0.f, 0.f};

  for (int ks = 0; ks < 16; ks++) {
    int k0 = ks * 32;
    __syncthreads();
    for (int i = tid; i < 1024; i += 256) {
      int row = i >> 3, seg = i & 7;
      float4 v = *(const float4*)(wbase + (size_t)row * 512 + k0 + seg * 4);
      u16* d = &Wb[row * 32 + seg * 4];
      d[0] = f2bfu(v.x); d[1] = f2bfu(v.y); d[2] = f2bfu(v.z); d[3] = f2bfu(v.w);
    }
    for (int i = tid; i < 512; i += 256) {
      int l = i >> 3, seg = i & 7;
      float4 v = make_float4(0.f, 0.f, 0.f, 0.f);
      if (img) {
        if (l < 49) v = *(const float4*)(xp + (size_t)(bidx * 49 + l) * 512 + k0 + seg * 4);
      } else {
        v = *(const float4*)(xp + (size_t)(bg * 64 + l) * 512 + k0 + seg * 4);
      }
      u16* d = &Xb[l * 32 + seg * 4];
      d[0] = f2bfu(v.x); d[1] = f2bfu(v.y); d[2] = f2bfu(v.z); d[3] = f2bfu(v.w);
    }
    __syncthreads();
    bf16x8 af[2], bfr[4];
#pragma unroll
    for (int mi = 0; mi < 2; mi++)
      af[mi] = *(const bf16x8*)&Wb[(w * 32 + mi * 16 + lm) * 32 + quad * 8];
#pragma unroll
    for (int nt = 0; nt < 4; nt++)
      bfr[nt] = *(const bf16x8*)&Xb[(nt * 16 + lm) * 32 + quad * 8];
#pragma unroll
    for (int mi = 0; mi < 2; mi++)
#pragma unroll
      for (int nt = 0; nt < 4; nt++)
        acc[mi][nt] = __builtin_amdgcn_mfma_f32_16x16x32_bf16(af[mi], bfr[nt], acc[mi][nt], 0, 0, 0);
  }
  __syncthreads();

#pragma unroll
  for (int mi = 0; mi < 2; mi++)
#pragma unroll
    for (int nt = 0; nt < 4; nt++)
#pragma unroll
      for (int r = 0; r < 4; r++) {
        int o_loc = w * 32 + mi * 16 + quad * 4 + r;
        int l     = nt * 16 + lm;
        float v = acc[mi][nt][r] * bnA[o_loc] + bnC[o_loc];
        hsB[o_loc * 88 + l] = f2bfu(v > 0.f ? v : 0.f);
      }
  __syncthreads();

  const int npass = img ? 1 : 2;
  const int nkt   = img ? 2 : 1;
  for (int p = 0; p < npass; p++) {
    f32x4 c2[2][2];
#pragma unroll
    for (int mi = 0; mi < 2; mi++)
#pragma unroll
      for (int nt2 = 0; nt2 < 2; nt2++) c2[mi][nt2] = (f32x4){0.f, 0.f, 0.f, 0.f};
    for (int kt = 0; kt < nkt; kt++) {
      int aoff = img ? kt * 32 : p * 32;
      int boff = img ? kt * 32 : 0;
      bf16x8 a2[2], b2[2];
#pragma unroll
      for (int mi = 0; mi < 2; mi++)
        a2[mi] = *(const bf16x8*)&hsB[(w * 32 + mi * 16 + lm) * 88 + aoff + quad * 8];
#pragma unroll
      for (int nt2 = 0; nt2 < 2; nt2++)
        b2[nt2] = *(const bf16x8*)&lw2[(nt2 * 16 + lm) * 72 + boff + quad * 8];
#pragma unroll
      for (int mi = 0; mi < 2; mi++)
#pragma unroll
        for (int nt2 = 0; nt2 < 2; nt2++)
          c2[mi][nt2] = __builtin_amdgcn_mfma_f32_16x16x32_bf16(a2[mi], b2[nt2], c2[mi][nt2], 0, 0, 0);
    }
#pragma unroll
    for (int mi = 0; mi < 2; mi++)
#pragma unroll
      for (int nt2 = 0; nt2 < 2; nt2++)
#pragma unroll
        for (int r = 0; r < 4; r++) {
          int kk    = nt2 * 16 + lm;
          int o_loc = w * 32 + mi * 16 + quad * 4 + r;
          float v = c2[mi][nt2][r] + lbs[kk];
          Cb[kk * 132 + o_loc] = v > 0.f ? v : 0.f;
        }
    __syncthreads();
    int b_out = img ? bidx : (bg * 2 + p);
    for (int i = tid; i < 4096; i += 256) {
      int kk = i >> 7, j = i & 127;
      out[((size_t)b_out * 128 + mod * 32 + kk) * 512 + ot * 128 + j] = Cb[kk * 132 + j];
    }
    if (p + 1 < npass) __syncthreads();
  }
}

__global__ __launch_bounds__(256) void fps_kernel(const float* __restrict__ pts,
                                                  int* __restrict__ idx_out)
{
  __shared__ float xs[4096], ys[4096], zs[4096];
  __shared__ float rv[4];
  __shared__ int   ri[4];
  __shared__ int   far_sh;
  const int b = blockIdx.x, tid = threadIdx.x;
  const float* pb = pts + (size_t)b * 4096 * 3;

  for (int i = tid; i < 12288; i += 256) {
    float v = pb[i];
    int n = i / 3, c = i - n * 3;
    float* dst = (c == 0) ? xs : (c == 1) ? ys : zs;
    dst[n] = v;
  }
  float dreg[16];
#pragma unroll
  for (int i = 0; i < 16; i++) dreg[i] = 1e10f;
  __syncthreads();

  uint2 k2 = threefry2x32(0u, 42u, 0u, 1u);
  uint2 r  = threefry2x32(k2.x, k2.y, 0u, (u32)b);
  int far  = (int)((r.x ^ r.y) & 4095u);

  for (int s = 0; s < 128; s++) {
    if (tid == 0) idx_out[b * 128 + s] = far;
    float cx = xs[far], cy = ys[far], cz = zs[far];
    float bestv = -1.f; int besti = 0x7FFFFFFF;
#pragma unroll
    for (int i = 0; i < 16; i++) {
      int n = tid + (i << 8);
      float dx = __fsub_rn(xs[n], cx);
      float dy = __fsub_rn(ys[n], cy);
      float dz = __fsub_rn(zs[n], cz);
      float d  = __fadd_rn(__fadd_rn(__fmul_rn(dx, dx), __fmul_rn(dy, dy)), __fmul_rn(dz, dz));
      float nd = fminf(dreg[i], d);
      dreg[i] = nd;
      if (nd > bestv) { bestv = nd; besti = n; }
    }
#pragma unroll
    for (int off = 1; off < 64; off <<= 1) {
      float ov = __shfl_xor(bestv, off, 64);
      int   oi = __shfl_xor(besti, off, 64);
      if (ov > bestv || (ov == bestv && oi < besti)) { bestv = ov; besti = oi; }
    }
    if ((tid & 63) == 0) { rv[tid >> 6] = bestv; ri[tid >> 6] = besti; }
    __syncthreads();
    if (tid == 0) {
      float bv = rv[0]; int bi = ri[0];
#pragma unroll
      for (int w = 1; w < 4; w++)
        if (rv[w] > bv || (rv[w] == bv && ri[w] < bi)) { bv = rv[w]; bi = ri[w]; }
      far_sh = bi;
    }
    __syncthreads();
    far = far_sh;
  }
}

// old f32 pe kernel (fallback only)
__global__ __launch_bounds__(256) void pe_kernel(
    const float* __restrict__ pts, const int* __restrict__ fps_idx,
    const float* __restrict__ w1, const float* __restrict__ b1,
    const float* __restrict__ g1, const float* __restrict__ bb1,
    const float* __restrict__ m1, const float* __restrict__ v1,
    const float* __restrict__ w2, const float* __restrict__ b2,
    const float* __restrict__ g2, const float* __restrict__ bb2,
    const float* __restrict__ m2, const float* __restrict__ v2,
    float* __restrict__ out)
{
  __shared__ float h1T[64][132];
  __shared__ float w2s[64][132];
  __shared__ float sc1s[128], C1s[128];
  const int ot = blockIdx.x;
  const int st = blockIdx.y;
  const int b  = blockIdx.z;
  const int tid = threadIdx.x;

  for (int i = tid; i < 64 * 32; i += 256) {
    int o = i >> 5, j = i & 31;
    float4 v = *(const float4*)(w2 + (size_t)(ot * 64 + o) * 128 + j * 4);
    *(float4*)&w2s[o][j * 4] = v;
  }
  if (tid < 128) {
    float sc = g1[tid] / sqrtf(v1[tid] + 1e-5f);
    sc1s[tid] = sc;
    C1s[tid]  = (b1[tid] - m1[tid]) * sc + bb1[tid];
  }
  __syncthreads();

  {
    int s_l = tid & 63;
    int cq  = tid >> 6;
    int s   = st * 64 + s_l;
    int n   = fps_idx[b * 128 + s];
    float px = pts[((size_t)b * 4096 + n) * 3 + 0];
    float py = pts[((size_t)b * 4096 + n) * 3 + 1];
    float pz = pts[((size_t)b * 4096 + n) * 3 + 2];
    for (int cc = 0; cc < 32; cc++) {
      int c = cq * 32 + cc;
      float d  = fmaf(pz, w1[c * 3 + 2], fmaf(py, w1[c * 3 + 1], px * w1[c * 3]));
      float h  = d * sc1s[c] + C1s[c];
      h1T[s_l][c] = h > 0.f ? h : 0.f;
    }
  }
  __syncthreads();

  const int tx = tid & 15, ty = tid >> 4;
  float acc[4][4];
#pragma unroll
  for (int j = 0; j < 4; j++)
#pragma unroll
    for (int i = 0; i < 4; i++) acc[j][i] = 0.f;

  for (int c = 0; c < 128; c += 4) {
    float4 wv[4];
#pragma unroll
    for (int j = 0; j < 4; j++) wv[j] = *(const float4*)&w2s[tx + 16 * j][c];
#pragma unroll
    for (int si = 0; si < 4; si++) {
      float4 hv = *(const float4*)&h1T[ty + 16 * si][c];
#pragma unroll
      for (int j = 0; j < 4; j++) {
        acc[j][si] = fmaf(hv.x, wv[j].x, acc[j][si]);
        acc[j][si] = fmaf(hv.y, wv[j].y, acc[j][si]);
        acc[j][si] = fmaf(hv.z, wv[j].z, acc[j][si]);
        acc[j][si] = fmaf(hv.w, wv[j].w, acc[j][si]);
      }
    }
  }

#pragma unroll
  for (int j = 0; j < 4; j++) {
    int o = ot * 64 + tx + 16 * j;
    float sc = g2[o] / sqrtf(v2[o] + 1e-5f);
    float C  = (b2[o] - m2[o]) * sc + bb2[o];
#pragma unroll
    for (int si = 0; si < 4; si++) {
      int s = st * 64 + ty + 16 * si;
      float v = acc[j][si] * sc + C;
      v = v > 0.f ? v : 0.f;
      size_t oi = ((size_t)b * 128 + s) * 512 + o;
      out[oi] = out[oi] + v;
    }
  }
}

// ======================================================================
extern "C" void kernel_launch(void* const* d_in, const int* in_sizes, int n_in,
                              void* d_out, int out_size, void* d_ws, size_t ws_size,
                              hipStream_t stream) {
  const float* rgb    = (const float*)d_in[0];
  const float* depth  = (const float*)d_in[1];
  const float* mmwave = (const float*)d_in[2];
  const float* lidar  = (const float*)d_in[3];
  const float* pts    = (const float*)d_in[4];
  const float* conv_w = (const float*)d_in[5];
  const float* conv_b = (const float*)d_in[6];
  const float* bn_g   = (const float*)d_in[7];
  const float* bn_b   = (const float*)d_in[8];
  const float* bn_m   = (const float*)d_in[9];
  const float* bn_v   = (const float*)d_in[10];
  const float* lwi    = (const float*)d_in[11];
  const float* lbi    = (const float*)d_in[12];
  const float* lwp    = (const float*)d_in[13];
  const float* lbp    = (const float*)d_in[14];
  const float* pw1    = (const float*)d_in[15];
  const float* pb1    = (const float*)d_in[16];
  const float* pg1    = (const float*)d_in[17];
  const float* pbb1   = (const float*)d_in[18];
  const float* pm1    = (const float*)d_in[19];
  const float* pv1    = (const float*)d_in[20];
  const float* pw2    = (const float*)d_in[21];
  const float* pb2    = (const float*)d_in[22];
  const float* pg2    = (const float*)d_in[23];
  const float* pbb2   = (const float*)d_in[24];
  const float* pm2    = (const float*)d_in[25];
  const float* pv2    = (const float*)d_in[26];
  float* out = (float*)d_out;
  int* fps_idx = (int*)d_ws;                       // [0, 131072)

  // ws layout: fps_idx 128KB | Wc 2MB | Xc 48MB | W2h 128KB | W2l 128KB |
  //            sc1C1 1KB | sc2C2 4KB
  const size_t O_WC   = 131072;
  const size_t O_XC   = 2228224;
  const size_t O_W2H  = 52559872;
  const size_t O_W2L  = 52690944;
  const size_t O_SC1  = 52822016;
  const size_t O_SC2  = 52823040;
  const size_t NEED   = 52827136;
  if (ws_size >= NEED) {
    u16*   Wc    = (u16*)((char*)d_ws + O_WC);
    u16*   Xc    = (u16*)((char*)d_ws + O_XC);
    u16*   W2h   = (u16*)((char*)d_ws + O_W2H);
    u16*   W2l   = (u16*)((char*)d_ws + O_W2L);
    float* sc1C1 = (float*)((char*)d_ws + O_SC1);
    float* sc2C2 = (float*)((char*)d_ws + O_SC2);
    convert_kernel<<<dim3(12833), 256, 0, stream>>>(rgb, depth, mmwave, lidar,
        conv_w, Wc, Xc, pw2, pg1, pbb1, pm1, pv1, pb1, pg2, pbb2, pm2, pv2, pb2,
        W2h, W2l, sc1C1, sc2C2);
    fused_kernel<<<dim3(3328), 256, 0, stream>>>(pts, fps_idx, Wc, Xc,
        conv_b, bn_g, bn_b, bn_m, bn_v, lwi, lbi, lwp, lbp, out);
    pe_mfma_kernel<<<dim3(8, 2, 256), 256, 0, stream>>>(pts, fps_idx, pw1,
        W2h, W2l, sc1C1, sc2C2, out);
  } else {
    branch_kernel<<<dim3(4, 768), 256, 0, stream>>>(rgb, depth, mmwave, lidar,
        conv_w, conv_b, bn_g, bn_b, bn_m, bn_v, lwi, lbi, lwp, lbp, out);
    fps_kernel<<<dim3(256), 256, 0, stream>>>(pts, fps_idx);
    pe_kernel<<<dim3(8, 2, 256), 256, 0, stream>>>(pts, fps_idx, pw1, pb1, pg1, pbb1, pm1, pv1,
        pw2, pb2, pg2, pbb2, pm2, pv2, out);
  }
}